// Round 9
// baseline (946.118 us; speedup 1.0000x reference)
//
#include <hip/hip_runtime.h>
#include <hip/hip_bf16.h>

#define BB 512
#define NA 58
#define LAT 64
#define HID 128
#define AF 10
#define NL 2
#define NN (BB*NA)      // 29696
#define NE (NN*16)      // 475136
#define ET 64           // edges per tile
#define NTILE (NE/ET)   // 7424
#define NCH 4           // T1 chunks
#define CHT (NTILE/NCH) // 1856 tiles per chunk
#define CE  (CHT*ET)    // 118784 edges per chunk
#define PBLK 1024

typedef __attribute__((ext_vector_type(8))) short s8;
typedef __attribute__((ext_vector_type(4))) float f4;

struct CvtDesc {
    const void* src[24];
    float*      dst[24];
    int         len[24];
};

struct PackJobs {
    const float* src[10];
    short*       dst[10];
    int          K[10];
    int          mode[10];
};

__device__ __forceinline__ float siluf(float x) {
    return x * __builtin_amdgcn_rcpf(1.0f + __expf(-x));
}

__device__ __forceinline__ short f2b(float x) {
    __hip_bfloat16 b = __float2bfloat16(x);
    return *(short*)&b;
}

__device__ __forceinline__ float b2f(short s) {
    return __uint_as_float(((unsigned int)(unsigned short)s) << 16);
}

// ---------------------------------------------------------------------------
__global__ void k_detect(const unsigned short* __restrict__ z16,
                         const unsigned int* __restrict__ e32,
                         int* __restrict__ flags) {
    __shared__ int sbf, si64;
    if (threadIdx.x == 0) { sbf = 0; si64 = 0; }
    __syncthreads();
    int c1 = 0, c2 = 0;
    for (int i = threadIdx.x; i < 1024; i += 256) {
        unsigned short v = z16[2*i];
        int e = (v >> 7) & 0xFF;
        if (e >= 100 && e <= 140) c1++;
        if (e32[2*i + 1] == 0u) c2++;
    }
    atomicAdd(&sbf, c1);
    atomicAdd(&si64, c2);
    __syncthreads();
    if (threadIdx.x == 0) {
        flags[0] = (sbf  > 600) ? 1 : 0;
        flags[1] = (si64 > 600) ? 1 : 0;
    }
}

__global__ void k_convert(CvtDesc d, const int* __restrict__ flags) {
    int a = blockIdx.y;
    int i = blockIdx.x * blockDim.x + threadIdx.x;
    int n = d.len[a];
    if (i >= n) return;
    if (flags[0]) {
        d.dst[a][i] = __bfloat162float(((const __hip_bfloat16*)d.src[a])[i]);
    } else {
        d.dst[a][i] = ((const float*)d.src[a])[i];
    }
}

__global__ void k_packall(PackJobs pj) {
    int j = blockIdx.y;
    int idx = blockIdx.x * 256 + threadIdx.x;
    const float* w = pj.src[j];
    short* o = pj.dst[j];
    if (pj.mode[j] == 0) {
        int K = pj.K[j];
        if (idx >= 128*K) return;
        int jj = idx & 7;
        int l  = (idx >> 3) & 63;
        int rest = idx >> 9;
        int KC = K >> 5;
        int kc = rest % KC;
        int nt = rest / KC;
        int n = nt*16 + (l & 15);
        int k = kc*32 + (l >> 4)*8 + jj;
        o[idx] = f2b(w[k*128 + n]);
    } else {
        if (idx >= 32768) return;
        int jj = idx & 7;
        int l  = (idx >> 3) & 63;
        int rest = idx >> 9;
        int kc = rest & 3;
        int nt = rest >> 2;
        int n = nt*16 + (l & 15);
        int k = kc*32 + (l >> 4)*8 + jj;
        float v = (n < 128) ? w[k*128 + n] : w[(128 + k)*128 + (n - 128)];
        o[idx] = f2b(v);
    }
}

// ---------------------------------------------------------------------------
__global__ void k_zero_cnt(int* __restrict__ cnt) {
    int i = blockIdx.x * 256 + threadIdx.x;
    if (i < NN) cnt[i] = 0;
}

__global__ void k_hist(const int* __restrict__ eidx, const int* __restrict__ flags,
                       int* __restrict__ cnt) {
    int e = blockIdx.x * 256 + threadIdx.x;
    if (e >= NE) return;
    int is64 = flags[1];
    int r = eidx[is64 ? 2*(long)e : (long)e];
    atomicAdd(&cnt[r], 1);
}

__global__ __launch_bounds__(1024) void k_scan(const int* __restrict__ cnt,
                                               int* __restrict__ rowStart,
                                               int* __restrict__ cursor) {
    __shared__ int part[1024];
    int t = threadIdx.x;
    int base = t * 29;                    // NN == 1024*29
    int loc[29];
    int s = 0;
    #pragma unroll
    for (int i = 0; i < 29; ++i) { loc[i] = s; s += cnt[base + i]; }
    part[t] = s;
    __syncthreads();
    for (int d = 1; d < 1024; d <<= 1) {
        int v = (t >= d) ? part[t - d] : 0;
        __syncthreads();
        part[t] += v;
        __syncthreads();
    }
    int pre = (t == 0) ? 0 : part[t - 1];
    #pragma unroll
    for (int i = 0; i < 29; ++i) {
        int v = pre + loc[i];
        rowStart[base + i] = v;
        cursor[base + i] = v;
    }
    if (t == 1023) rowStart[NN] = pre + s;
}

__global__ void k_scatter(const int* __restrict__ eidx, const int* __restrict__ flags,
                          int* __restrict__ cursor,
                          int* __restrict__ rS, int* __restrict__ cS) {
    int e = blockIdx.x * 256 + threadIdx.x;
    if (e >= NE) return;
    int is64 = flags[1];
    long ge = e, gc = (long)e + NE;
    int r = eidx[is64 ? 2*ge : ge];
    int c = eidx[is64 ? 2*gc : gc];
    int p = atomicAdd(&cursor[r], 1);
    rS[p] = r; cS[p] = c;
}

// ---------------------------------------------------------------------------
__global__ void k_hz(const float* __restrict__ z, const float* __restrict__ lw,
                     const float* __restrict__ lb, float* __restrict__ hz) {
    __shared__ float zs[LAT];
    int b = blockIdx.x;
    int c = threadIdx.x;
    if (c < LAT) zs[c] = z[b*LAT + c];
    __syncthreads();
    float acc = lb[c];
    #pragma unroll
    for (int k = 0; k < LAT; ++k) acc += zs[k] * lw[k*HID + c];
    hz[b*HID + c] = acc;
}

__global__ void k_init2(const float* __restrict__ hz, const float* __restrict__ at,
                        const float* __restrict__ aw, const float* __restrict__ ab,
                        const float* __restrict__ ic,
                        float* __restrict__ pos, short* __restrict__ hb) {
    __shared__ float ats[AF];
    int n = blockIdx.x;
    int c = threadIdx.x;
    int b = n / NA;
    if (c < AF) ats[c] = at[n*AF + c];
    __syncthreads();
    float acc = hz[b*HID + c] + ab[c];
    #pragma unroll
    for (int f = 0; f < AF; ++f) acc += ats[f] * aw[f*HID + c];
    hb[(long)n*HID + c] = f2b(acc);
    if (c < 3) {
        int a = n % NA;
        pos[n*3 + c] = ic[a*3 + c];
    }
}

// ---------------------------------------------------------------------------
// H1 = hb @ [w1a|w1b] (+ b1 on a-half) -> [NN][256] bf16.  Also zeros agg/upd.
__global__ __launch_bounds__(256) void k_pre(
    const short* __restrict__ hb, const short* __restrict__ wcat,
    const float* __restrict__ b1, short* __restrict__ H1,
    float* __restrict__ agg, float* __restrict__ upd)
{
    __shared__ short x[64][136];
    const int tid = threadIdx.x;
    const int n0 = blockIdx.x * 64;

    // zero agg/upd for this layer (grid-stride; completes before kernel end)
    {
        long base = (long)blockIdx.x*256 + tid;
        f4* a4 = (f4*)agg;
        for (long j = base; j < (long)NN*HID/4; j += (long)gridDim.x*256) a4[j] = (f4)0.f;
        if (base < NN*3) upd[base] = 0.f;
    }

    #pragma unroll
    for (int it = 0; it < 4; ++it) {
        int idx = it*256 + tid;
        int e = idx >> 4, q = idx & 15;
        *(int4*)&x[e][q*8] = *(const int4*)(hb + (long)(n0+e)*HID + q*8);
    }
    __syncthreads();

    const int l = tid & 63, w = tid >> 6;
    const int l16 = l & 15, quad = l >> 4;

    f4 acc[4][4];
    #pragma unroll
    for (int mt = 0; mt < 4; ++mt)
        #pragma unroll
        for (int nt4 = 0; nt4 < 4; ++nt4) acc[mt][nt4] = (f4)0.f;

    #pragma unroll
    for (int kc = 0; kc < 4; ++kc) {
        s8 a[4];
        #pragma unroll
        for (int mt = 0; mt < 4; ++mt)
            a[mt] = *(const s8*)&x[mt*16 + l16][kc*32 + quad*8];
        #pragma unroll
        for (int nt4 = 0; nt4 < 4; ++nt4) {
            int nt = w*4 + nt4;
            s8 b = *(const s8*)(wcat + (((size_t)nt*4 + kc)*64 + l)*8);
            #pragma unroll
            for (int mt = 0; mt < 4; ++mt)
                acc[mt][nt4] = __builtin_amdgcn_mfma_f32_16x16x32_bf16(a[mt], b, acc[mt][nt4], 0, 0, 0);
        }
    }
    #pragma unroll
    for (int nt4 = 0; nt4 < 4; ++nt4) {
        int col = (w*4 + nt4)*16 + l16;
        float bias = (col < 128) ? b1[col] : 0.f;
        #pragma unroll
        for (int mt = 0; mt < 4; ++mt)
            #pragma unroll
            for (int i = 0; i < 4; ++i) {
                int row = mt*16 + quad*4 + i;
                H1[(long)(n0 + row)*256 + col] = f2b(acc[mt][nt4][i] + bias);
            }
    }
}

// ---------------------------------------------------------------------------
// Pass A: T1[e_local][128] = silu(H1a[r] + H1b[c] + d2*w1c)  (streaming)
// one thread per (edge, 16B chunk); grid = CE*16/256 blocks.
__global__ __launch_bounds__(256) void k_t1(
    const short* __restrict__ H1, const int* __restrict__ rS,
    const int* __restrict__ cS, const float* __restrict__ pos,
    const float* __restrict__ w1c, short* __restrict__ T1, int e0)
{
    long idx = (long)blockIdx.x*256 + threadIdx.x;
    long el = idx >> 4;                  // local edge in chunk
    long e  = e0 + el;                   // global edge
    int q = (int)idx & 15;
    int r = rS[e], c = cS[e];
    float rx = pos[r*3+0] - pos[c*3+0];
    float ry = pos[r*3+1] - pos[c*3+1];
    float rz = pos[r*3+2] - pos[c*3+2];
    float d2 = fminf(fmaxf(rx*rx + ry*ry + rz*rz, 1e-6f), 1e6f);
    s8 va = *(const s8*)(H1 + (long)r*256 + q*8);
    s8 vb = *(const s8*)(H1 + (long)c*256 + 128 + q*8);
    f4 w0 = *(const f4*)(w1c + q*8);
    f4 w1 = *(const f4*)(w1c + q*8 + 4);
    s8 o;
    #pragma unroll
    for (int j = 0; j < 8; ++j) {
        float wvj = (j < 4) ? w0[j & 3] : w1[j & 3];
        o[j] = f2b(siluf(b2f(va[j]) + b2f(vb[j]) + d2*wvj));
    }
    *(s8*)(T1 + el*128 + q*8) = o;
}

// ---------------------------------------------------------------------------
// Pass B: stages 2-3 + reductions. A-frags straight from global T1.
// 2 barriers per tile.
__global__ __launch_bounds__(256, 4) void k_edgeB(
    const short* __restrict__ T1,
    const int* __restrict__ rS, const int* __restrict__ cS,
    const float* __restrict__ pos,
    const short* __restrict__ w2p, const float* __restrict__ b2,
    const short* __restrict__ c1p, const float* __restrict__ cb1,
    const float* __restrict__ cw2,
    float* __restrict__ agg, float* __restrict__ upd, int t0)
{
    __shared__ short mm[ET][136];
    __shared__ int   rIs[ET];
    __shared__ float sred[ET];

    const int tid = threadIdx.x;
    const int l = tid & 63, w = tid >> 6;
    const int l16 = l & 15, quad = l >> 4;
    const int c0 = (2*w)*16 + l16, c1c = (2*w+1)*16 + l16;
    const int half = tid >> 7, ch = tid & 127;

    s8 w2f[8], c1f[8];
    #pragma unroll
    for (int kc = 0; kc < 4; ++kc) {
        w2f[kc]     = *(const s8*)(w2p + (((size_t)(2*w)*4 + kc)*64 + l)*8);
        w2f[4 + kc] = *(const s8*)(w2p + (((size_t)(2*w+1)*4 + kc)*64 + l)*8);
        c1f[kc]     = *(const s8*)(c1p + (((size_t)(2*w)*4 + kc)*64 + l)*8);
        c1f[4 + kc] = *(const s8*)(c1p + (((size_t)(2*w+1)*4 + kc)*64 + l)*8);
    }
    const float bia2_0 = b2[c0],  bia2_1 = b2[c1c];
    const float biac_0 = cb1[c0], biac_1 = cb1[c1c];
    const float cw0    = cw2[c0], cw1v   = cw2[c1c];

    if (tid < ET) sred[tid] = 0.f;

    for (int t = t0 + blockIdx.x; t < t0 + CHT; t += PBLK) {
        const long tb  = (long)(t - t0) * ET;    // T1 local row base
        const long geb = (long)t * ET;           // global edge base
        if (tid < ET) rIs[tid] = rS[geb + tid];

        // ---- stage 2: m = silu(t1 @ w2 + b2), A-frags from global T1
        {
            f4 acc[4][2];
            #pragma unroll
            for (int mt = 0; mt < 4; ++mt) { acc[mt][0] = (f4)0.f; acc[mt][1] = (f4)0.f; }
            #pragma unroll
            for (int kc = 0; kc < 4; ++kc) {
                #pragma unroll
                for (int mt = 0; mt < 4; ++mt) {
                    s8 a = *(const s8*)(T1 + (tb + mt*16 + l16)*128 + kc*32 + quad*8);
                    acc[mt][0] = __builtin_amdgcn_mfma_f32_16x16x32_bf16(a, w2f[kc],     acc[mt][0], 0, 0, 0);
                    acc[mt][1] = __builtin_amdgcn_mfma_f32_16x16x32_bf16(a, w2f[4 + kc], acc[mt][1], 0, 0, 0);
                }
            }
            #pragma unroll
            for (int mt = 0; mt < 4; ++mt) {
                #pragma unroll
                for (int i = 0; i < 4; ++i) {
                    int row = mt*16 + quad*4 + i;
                    mm[row][c0]  = f2b(siluf(acc[mt][0][i] + bia2_0));
                    mm[row][c1c] = f2b(siluf(acc[mt][1][i] + bia2_1));
                }
            }
        }
        __syncthreads();                 // (C) mm + rIs ready

        // ---- stage 3: c1 = silu(mm @ cw1 + cb1); dot cw2 -> sred
        {
            f4 acc[4][2];
            #pragma unroll
            for (int mt = 0; mt < 4; ++mt) { acc[mt][0] = (f4)0.f; acc[mt][1] = (f4)0.f; }
            #pragma unroll
            for (int kc = 0; kc < 4; ++kc) {
                #pragma unroll
                for (int mt = 0; mt < 4; ++mt) {
                    s8 a = *(const s8*)&mm[mt*16 + l16][kc*32 + quad*8];
                    acc[mt][0] = __builtin_amdgcn_mfma_f32_16x16x32_bf16(a, c1f[kc],     acc[mt][0], 0, 0, 0);
                    acc[mt][1] = __builtin_amdgcn_mfma_f32_16x16x32_bf16(a, c1f[4 + kc], acc[mt][1], 0, 0, 0);
                }
            }
            #pragma unroll
            for (int mt = 0; mt < 4; ++mt) {
                #pragma unroll
                for (int i = 0; i < 4; ++i) {
                    float p = siluf(acc[mt][0][i] + biac_0) * cw0
                            + siluf(acc[mt][1][i] + biac_1) * cw1v;
                    p += __shfl_xor(p, 1);
                    p += __shfl_xor(p, 2);
                    p += __shfl_xor(p, 4);
                    p += __shfl_xor(p, 8);
                    if (l16 == 0) {
                        int row = mt*16 + quad*4 + i;
                        atomicAdd(&sred[row], p);
                    }
                }
            }
        }

        // ---- segmented agg reduction over sorted rows (reads mm bf16)
        {
            int e0s = half * 32;
            int cur = rIs[e0s];
            float a = 0.f;
            #pragma unroll
            for (int e = e0s; e < e0s + 32; ++e) {
                int r = rIs[e];
                if (r != cur) {
                    atomicAdd(&agg[(long)cur*HID + ch], a);
                    a = 0.f; cur = r;
                }
                a += b2f(mm[e][ch]);
            }
            atomicAdd(&agg[(long)cur*HID + ch], a);
        }
        __syncthreads();                 // (D) sred done, mm consumed

        if (tid < ET) {
            long ge = geb + tid;
            float cwv = fminf(fmaxf(sred[tid], -1.f), 1.f);
            sred[tid] = 0.f;             // re-arm for next tile (pre next-C)
            int r = rS[ge], c = cS[ge];
            float rx = pos[r*3+0] - pos[c*3+0];
            float ry = pos[r*3+1] - pos[c*3+1];
            float rz = pos[r*3+2] - pos[c*3+2];
            atomicAdd(&upd[r*3+0], cwv*rx);
            atomicAdd(&upd[r*3+1], cwv*ry);
            atomicAdd(&upd[r*3+2], cwv*rz);
        }
    }
}

// ---------------------------------------------------------------------------
__global__ __launch_bounds__(256) void k_node_mfma(
    short* __restrict__ hb, const float* __restrict__ agg,
    const short* __restrict__ w1p, const float* __restrict__ b1n,
    const short* __restrict__ w2p, const float* __restrict__ b2n,
    const float* __restrict__ lg, const float* __restrict__ lb,
    float* __restrict__ pos, const float* __restrict__ upd,
    const int* __restrict__ rowStart)
{
    __shared__ short x[64][264];
    __shared__ short t1[64][144];
    __shared__ float mus[64], rstds[64];
    float (*hn)[132] = (float (*)[132])&x[0][0];

    const int tid = threadIdx.x;
    const int n0 = blockIdx.x * 64;

    #pragma unroll
    for (int it = 0; it < 4; ++it) {
        int idx = it*256 + tid;
        int e = idx >> 4, q = idx & 15;
        *(int4*)&x[e][q*8] = *(const int4*)(hb + (long)(n0+e)*HID + q*8);
    }
    #pragma unroll
    for (int it = 0; it < 8; ++it) {
        int idx = it*256 + tid;
        int e = idx >> 5, q = idx & 31;
        float4 v = *(const float4*)(agg + (long)(n0+e)*HID + q*4);
        short4 sv;
        sv.x = f2b(v.x); sv.y = f2b(v.y); sv.z = f2b(v.z); sv.w = f2b(v.w);
        *(short4*)&x[e][128 + q*4] = sv;
    }
    __syncthreads();

    const int l = tid & 63, w = tid >> 6;
    const int l16 = l & 15, quad = l >> 4;
    const int nt0 = 2*w, nt1 = 2*w + 1;
    const int c0 = nt0*16 + l16, c1c = nt1*16 + l16;

    {
        f4 acc[4][2];
        #pragma unroll
        for (int mt = 0; mt < 4; ++mt) { acc[mt][0] = (f4)0.f; acc[mt][1] = (f4)0.f; }
        #pragma unroll
        for (int kc = 0; kc < 8; ++kc) {
            s8 b0  = *(const s8*)(w1p + (((size_t)nt0*8 + kc)*64 + l)*8);
            s8 b1f = *(const s8*)(w1p + (((size_t)nt1*8 + kc)*64 + l)*8);
            #pragma unroll
            for (int mt = 0; mt < 4; ++mt) {
                s8 a = *(const s8*)&x[mt*16 + l16][kc*32 + quad*8];
                acc[mt][0] = __builtin_amdgcn_mfma_f32_16x16x32_bf16(a, b0,  acc[mt][0], 0, 0, 0);
                acc[mt][1] = __builtin_amdgcn_mfma_f32_16x16x32_bf16(a, b1f, acc[mt][1], 0, 0, 0);
            }
        }
        float bia0 = b1n[c0], bia1 = b1n[c1c];
        #pragma unroll
        for (int mt = 0; mt < 4; ++mt) {
            #pragma unroll
            for (int i = 0; i < 4; ++i) {
                int row = mt*16 + quad*4 + i;
                t1[row][c0]  = f2b(siluf(acc[mt][0][i] + bia0));
                t1[row][c1c] = f2b(siluf(acc[mt][1][i] + bia1));
            }
        }
    }
    __syncthreads();

    {
        f4 acc[4][2];
        #pragma unroll
        for (int mt = 0; mt < 4; ++mt) { acc[mt][0] = (f4)0.f; acc[mt][1] = (f4)0.f; }
        #pragma unroll
        for (int kc = 0; kc < 4; ++kc) {
            s8 b0  = *(const s8*)(w2p + (((size_t)nt0*4 + kc)*64 + l)*8);
            s8 b1f = *(const s8*)(w2p + (((size_t)nt1*4 + kc)*64 + l)*8);
            #pragma unroll
            for (int mt = 0; mt < 4; ++mt) {
                s8 a = *(const s8*)&t1[mt*16 + l16][kc*32 + quad*8];
                acc[mt][0] = __builtin_amdgcn_mfma_f32_16x16x32_bf16(a, b0,  acc[mt][0], 0, 0, 0);
                acc[mt][1] = __builtin_amdgcn_mfma_f32_16x16x32_bf16(a, b1f, acc[mt][1], 0, 0, 0);
            }
        }
        float bia0 = b2n[c0], bia1 = b2n[c1c];
        __syncthreads();
        #pragma unroll
        for (int mt = 0; mt < 4; ++mt) {
            #pragma unroll
            for (int i = 0; i < 4; ++i) {
                int row = mt*16 + quad*4 + i;
                hn[row][c0]  = acc[mt][0][i] + bia0;
                hn[row][c1c] = acc[mt][1][i] + bia1;
            }
        }
    }
    __syncthreads();

    {
        int r = tid >> 2, part = tid & 3;
        float s = 0.f, q = 0.f;
        #pragma unroll
        for (int j = 0; j < 32; ++j) {
            float v = hn[r][part + 4*j];
            s += v; q += v*v;
        }
        s += __shfl_xor(s, 1); q += __shfl_xor(q, 1);
        s += __shfl_xor(s, 2); q += __shfl_xor(q, 2);
        if (part == 0) {
            float mu = s * (1.0f/HID);
            float var = q * (1.0f/HID) - mu*mu;
            mus[r] = mu;
            rstds[r] = rsqrtf(var + 1e-5f);
        }
    }
    __syncthreads();

    #pragma unroll
    for (int it = 0; it < 32; ++it) {
        int idx = it*256 + tid;
        int r = idx >> 7, c = idx & 127;
        float v = (hn[r][c] - mus[r]) * rstds[r] * lg[c] + lb[c];
        hb[(long)(n0 + r)*HID + c] = f2b(v);
    }
    if (tid < 192) {
        int i = tid / 3, d = tid - i*3;
        int n = n0 + i;
        float dg = (float)(rowStart[n+1] - rowStart[n]);
        pos[n*3+d] += upd[n*3+d] / (dg + 1e-6f);
    }
}

// ---------------------------------------------------------------------------
__global__ void k_head(const short* __restrict__ hb, const float* __restrict__ pos,
                       const float* __restrict__ w1, const float* __restrict__ b1,
                       const float* __restrict__ w2, const float* __restrict__ b2,
                       void* __restrict__ out, const int* __restrict__ flags)
{
    __shared__ float hs[4][HID];
    __shared__ float t[4][64];
    const int tid = threadIdx.x;
    const int n0 = blockIdx.x * 4;
    for (int i = tid; i < 4*HID; i += 256)
        hs[i >> 7][i & 127] = b2f(hb[(long)n0*HID + i]);
    __syncthreads();
    const int s = tid >> 6, c = tid & 63;
    float acc = b1[c];
    for (int k4 = 0; k4 < 32; ++k4) {
        int k = k4*4;
        float wa = w1[(k+0)*64 + c];
        float wb = w1[(k+1)*64 + c];
        float wc = w1[(k+2)*64 + c];
        float wd = w1[(k+3)*64 + c];
        float4 v = *(const float4*)&hs[s][k];
        acc += v.x*wa + v.y*wb + v.z*wc + v.w*wd;
    }
    t[s][c] = siluf(acc);
    __syncthreads();
    if (c < 3) {
        float a2 = b2[c];
        #pragma unroll
        for (int k = 0; k < 64; ++k) a2 += t[s][k] * w2[k*3 + c];
        int n = n0 + s;
        float v = pos[n*3+c] + a2;
        if (flags[0]) ((__hip_bfloat16*)out)[n*3+c] = __float2bfloat16(v);
        else          ((float*)out)[n*3+c] = v;
    }
}

// ---------------------------------------------------------------------------
extern "C" void kernel_launch(void* const* d_in, const int* in_sizes, int n_in,
                              void* d_out, int out_size, void* d_ws, size_t ws_size,
                              hipStream_t stream)
{
    (void)in_sizes; (void)n_in; (void)out_size; (void)ws_size;

    int* flags = (int*)d_ws;
    float* base = (float*)d_ws;
    size_t off = 64;
    auto alloc = [&](size_t n) { float* p = base + off; off += (n + 63) & ~63ull; return p; };

    static const int aidx[24] = {0,1,3,4,5,6,7,8,9,10,11,12,13,14,15,16,17,18,19,20,21,22,23,24};
    static const int alen[24] = {
        BB*LAT, NN*AF, NA*3, LAT*HID, HID, AF*HID, HID,
        NL*257*HID, NL*HID, NL*HID*HID, NL*HID,
        NL*256*HID, NL*HID, NL*HID*HID, NL*HID,
        NL*HID*HID, NL*HID, NL*HID, NL*HID, NL*HID,
        HID*64, 64, 64*3, 3
    };
    CvtDesc cd;
    float* fp[24];
    for (int a = 0; a < 24; ++a) {
        fp[a] = alloc((size_t)alen[a]);
        cd.src[a] = d_in[aidx[a]];
        cd.dst[a] = fp[a];
        cd.len[a] = alen[a];
    }
    float* agg = alloc((size_t)NN*HID);
    float* hz  = alloc((size_t)BB*HID);
    float* pos = alloc((size_t)NN*3);
    float* upd = alloc((size_t)NN*3);
    short* hb  = (short*)alloc((size_t)NN*HID/2);
    short* H1  = (short*)alloc((size_t)NN*256/2);
    short* T1  = (short*)alloc((size_t)CE*128/2);
    short* wcatp = (short*)alloc((size_t)NL*32768/2);
    short* w2p = (short*)alloc((size_t)NL*16384/2);
    short* c1p = (short*)alloc((size_t)NL*16384/2);
    short* nw1p = (short*)alloc((size_t)NL*32768/2);
    short* nw2p = (short*)alloc((size_t)NL*16384/2);
    int* cnt      = (int*)alloc((size_t)NN);
    int* rowStart = (int*)alloc((size_t)NN + 1);
    int* cursor   = (int*)alloc((size_t)NN);
    int* rS       = (int*)alloc((size_t)NE);
    int* cS       = (int*)alloc((size_t)NE);
    const int* eidx = (const int*)d_in[2];

    k_detect<<<1, 256, 0, stream>>>((const unsigned short*)d_in[0],
                                    (const unsigned int*)d_in[2], flags);
    k_convert<<<dim3((NN*AF + 255)/256, 24), 256, 0, stream>>>(cd, flags);

    PackJobs pj;
    for (int l = 0; l < NL; ++l) {
        int b5 = l*5;
        pj.src[b5+0] = fp[7]  + (size_t)l*257*HID; pj.dst[b5+0] = wcatp + (size_t)l*32768; pj.K[b5+0] = 256; pj.mode[b5+0] = 1;
        pj.src[b5+1] = fp[9]  + (size_t)l*HID*HID; pj.dst[b5+1] = w2p   + (size_t)l*16384; pj.K[b5+1] = 128; pj.mode[b5+1] = 0;
        pj.src[b5+2] = fp[15] + (size_t)l*HID*HID; pj.dst[b5+2] = c1p   + (size_t)l*16384; pj.K[b5+2] = 128; pj.mode[b5+2] = 0;
        pj.src[b5+3] = fp[11] + (size_t)l*256*HID; pj.dst[b5+3] = nw1p  + (size_t)l*32768; pj.K[b5+3] = 256; pj.mode[b5+3] = 0;
        pj.src[b5+4] = fp[13] + (size_t)l*HID*HID; pj.dst[b5+4] = nw2p  + (size_t)l*16384; pj.K[b5+4] = 128; pj.mode[b5+4] = 0;
    }
    k_packall<<<dim3(128, 10), 256, 0, stream>>>(pj);

    // counting sort edges by row
    k_zero_cnt<<<(NN + 255)/256, 256, 0, stream>>>(cnt);
    k_hist<<<(NE + 255)/256, 256, 0, stream>>>(eidx, flags, cnt);
    k_scan<<<1, 1024, 0, stream>>>(cnt, rowStart, cursor);
    k_scatter<<<(NE + 255)/256, 256, 0, stream>>>(eidx, flags, cursor, rS, cS);

    k_hz<<<BB, HID, 0, stream>>>(fp[0], fp[3], fp[4], hz);
    k_init2<<<NN, HID, 0, stream>>>(hz, fp[1], fp[5], fp[6], fp[2], pos, hb);

    for (int l = 0; l < NL; ++l) {
        k_pre<<<NN/64, 256, 0, stream>>>(hb, wcatp + (size_t)l*32768,
                                         fp[8] + (size_t)l*HID, H1, agg, upd);
        const float* w1c = fp[7] + (size_t)l*257*HID + 256*HID;
        for (int chk = 0; chk < NCH; ++chk) {
            k_t1<<<CE*16/256, 256, 0, stream>>>(H1, rS, cS, pos, w1c, T1, chk*CE);
            k_edgeB<<<PBLK, 256, 0, stream>>>(T1, rS, cS, pos,
                w2p + (size_t)l*16384, fp[10] + (size_t)l*HID,
                c1p + (size_t)l*16384, fp[16] + (size_t)l*HID,
                fp[17] + (size_t)l*HID,
                agg, upd, chk*CHT);
        }
        k_node_mfma<<<NN/64, 256, 0, stream>>>(hb, agg,
            nw1p + (size_t)l*32768, fp[12] + (size_t)l*HID,
            nw2p + (size_t)l*16384, fp[14] + (size_t)l*HID,
            fp[18] + (size_t)l*HID, fp[19] + (size_t)l*HID,
            pos, upd, rowStart);
    }
    k_head<<<NN/4, 256, 0, stream>>>(hb, pos, fp[20], fp[21], fp[22], fp[23],
                                     d_out, flags);
}

// Round 10
// 726.312 us; speedup vs baseline: 1.3026x; 1.3026x over previous
//
#include <hip/hip_runtime.h>
#include <hip/hip_bf16.h>

#define BB 512
#define NA 58
#define LAT 64
#define HID 128
#define AF 10
#define NL 2
#define NN (BB*NA)      // 29696
#define NE (NN*16)      // 475136
#define ET 64           // edges per tile
#define NTILE (NE/ET)   // 7424
#define PBLK 1024       // persistent blocks (4 per CU)

typedef __attribute__((ext_vector_type(8))) short s8;
typedef __attribute__((ext_vector_type(4))) float f4;

struct CvtDesc {
    const void* src[24];
    float*      dst[24];
    int         len[24];
};

struct PackJobs {
    const float* src[10];
    short*       dst[10];
    int          K[10];
    int          mode[10];
};

__device__ __forceinline__ float siluf(float x) {
    return x * __builtin_amdgcn_rcpf(1.0f + __expf(-x));
}

__device__ __forceinline__ short f2b(float x) {
    __hip_bfloat16 b = __float2bfloat16(x);
    return *(short*)&b;
}

__device__ __forceinline__ float b2f(short s) {
    return __uint_as_float(((unsigned int)(unsigned short)s) << 16);
}

// ---------------------------------------------------------------------------
__global__ void k_detect(const unsigned short* __restrict__ z16,
                         const unsigned int* __restrict__ e32,
                         int* __restrict__ flags) {
    __shared__ int sbf, si64;
    if (threadIdx.x == 0) { sbf = 0; si64 = 0; }
    __syncthreads();
    int c1 = 0, c2 = 0;
    for (int i = threadIdx.x; i < 1024; i += 256) {
        unsigned short v = z16[2*i];
        int e = (v >> 7) & 0xFF;
        if (e >= 100 && e <= 140) c1++;
        if (e32[2*i + 1] == 0u) c2++;
    }
    atomicAdd(&sbf, c1);
    atomicAdd(&si64, c2);
    __syncthreads();
    if (threadIdx.x == 0) {
        flags[0] = (sbf  > 600) ? 1 : 0;
        flags[1] = (si64 > 600) ? 1 : 0;
    }
}

__global__ void k_convert(CvtDesc d, const int* __restrict__ flags) {
    int a = blockIdx.y;
    int i = blockIdx.x * blockDim.x + threadIdx.x;
    int n = d.len[a];
    if (i >= n) return;
    if (flags[0]) {
        d.dst[a][i] = __bfloat162float(((const __hip_bfloat16*)d.src[a])[i]);
    } else {
        d.dst[a][i] = ((const float*)d.src[a])[i];
    }
}

__global__ void k_packall(PackJobs pj) {
    int j = blockIdx.y;
    int idx = blockIdx.x * 256 + threadIdx.x;
    const float* w = pj.src[j];
    short* o = pj.dst[j];
    if (pj.mode[j] == 0) {
        int K = pj.K[j];
        if (idx >= 128*K) return;
        int jj = idx & 7;
        int l  = (idx >> 3) & 63;
        int rest = idx >> 9;
        int KC = K >> 5;
        int kc = rest % KC;
        int nt = rest / KC;
        int n = nt*16 + (l & 15);
        int k = kc*32 + (l >> 4)*8 + jj;
        o[idx] = f2b(w[k*128 + n]);
    } else {
        if (idx >= 32768) return;
        int jj = idx & 7;
        int l  = (idx >> 3) & 63;
        int rest = idx >> 9;
        int kc = rest & 3;
        int nt = rest >> 2;
        int n = nt*16 + (l & 15);
        int k = kc*32 + (l >> 4)*8 + jj;
        float v = (n < 128) ? w[k*128 + n] : w[(128 + k)*128 + (n - 128)];
        o[idx] = f2b(v);
    }
}

// ---------------------------------------------------------------------------
__global__ void k_zero_cnt(int* __restrict__ cnt) {
    int i = blockIdx.x * 256 + threadIdx.x;
    if (i < NN) cnt[i] = 0;
}

__global__ void k_hist(const int* __restrict__ eidx, const int* __restrict__ flags,
                       int* __restrict__ cnt) {
    int e = blockIdx.x * 256 + threadIdx.x;
    if (e >= NE) return;
    int is64 = flags[1];
    int r = eidx[is64 ? 2*(long)e : (long)e];
    atomicAdd(&cnt[r], 1);
}

__global__ __launch_bounds__(1024) void k_scan(const int* __restrict__ cnt,
                                               int* __restrict__ rowStart,
                                               int* __restrict__ cursor) {
    __shared__ int part[1024];
    int t = threadIdx.x;
    int base = t * 29;                    // NN == 1024*29
    int loc[29];
    int s = 0;
    #pragma unroll
    for (int i = 0; i < 29; ++i) { loc[i] = s; s += cnt[base + i]; }
    part[t] = s;
    __syncthreads();
    for (int d = 1; d < 1024; d <<= 1) {
        int v = (t >= d) ? part[t - d] : 0;
        __syncthreads();
        part[t] += v;
        __syncthreads();
    }
    int pre = (t == 0) ? 0 : part[t - 1];
    #pragma unroll
    for (int i = 0; i < 29; ++i) {
        int v = pre + loc[i];
        rowStart[base + i] = v;
        cursor[base + i] = v;
    }
    if (t == 1023) rowStart[NN] = pre + s;
}

__global__ void k_scatter(const int* __restrict__ eidx, const int* __restrict__ flags,
                          int* __restrict__ cursor,
                          int* __restrict__ rS, int* __restrict__ cS) {
    int e = blockIdx.x * 256 + threadIdx.x;
    if (e >= NE) return;
    int is64 = flags[1];
    long ge = e, gc = (long)e + NE;
    int r = eidx[is64 ? 2*ge : ge];
    int c = eidx[is64 ? 2*gc : gc];
    int p = atomicAdd(&cursor[r], 1);
    rS[p] = r; cS[p] = c;
}

// ---------------------------------------------------------------------------
__global__ void k_hz(const float* __restrict__ z, const float* __restrict__ lw,
                     const float* __restrict__ lb, float* __restrict__ hz) {
    __shared__ float zs[LAT];
    int b = blockIdx.x;
    int c = threadIdx.x;
    if (c < LAT) zs[c] = z[b*LAT + c];
    __syncthreads();
    float acc = lb[c];
    #pragma unroll
    for (int k = 0; k < LAT; ++k) acc += zs[k] * lw[k*HID + c];
    hz[b*HID + c] = acc;
}

__global__ void k_init2(const float* __restrict__ hz, const float* __restrict__ at,
                        const float* __restrict__ aw, const float* __restrict__ ab,
                        const float* __restrict__ ic,
                        float* __restrict__ pos, short* __restrict__ hb) {
    __shared__ float ats[AF];
    int n = blockIdx.x;
    int c = threadIdx.x;
    int b = n / NA;
    if (c < AF) ats[c] = at[n*AF + c];
    __syncthreads();
    float acc = hz[b*HID + c] + ab[c];
    #pragma unroll
    for (int f = 0; f < AF; ++f) acc += ats[f] * aw[f*HID + c];
    hb[(long)n*HID + c] = f2b(acc);
    if (c < 3) {
        int a = n % NA;
        pos[n*3 + c] = ic[a*3 + c];
    }
}

// ---------------------------------------------------------------------------
// H1 = hb @ [w1a|w1b] (+ b1 on a-half) -> [NN][256] bf16.  Also zeros agg/upd.
__global__ __launch_bounds__(256) void k_pre(
    const short* __restrict__ hb, const short* __restrict__ wcat,
    const float* __restrict__ b1, short* __restrict__ H1,
    float* __restrict__ agg, float* __restrict__ upd)
{
    __shared__ short x[64][136];
    const int tid = threadIdx.x;
    const int n0 = blockIdx.x * 64;

    {
        long base = (long)blockIdx.x*256 + tid;
        f4* a4 = (f4*)agg;
        for (long j = base; j < (long)NN*HID/4; j += (long)gridDim.x*256) a4[j] = (f4)0.f;
        if (base < NN*3) upd[base] = 0.f;
    }

    #pragma unroll
    for (int it = 0; it < 4; ++it) {
        int idx = it*256 + tid;
        int e = idx >> 4, q = idx & 15;
        *(int4*)&x[e][q*8] = *(const int4*)(hb + (long)(n0+e)*HID + q*8);
    }
    __syncthreads();

    const int l = tid & 63, w = tid >> 6;
    const int l16 = l & 15, quad = l >> 4;

    f4 acc[4][4];
    #pragma unroll
    for (int mt = 0; mt < 4; ++mt)
        #pragma unroll
        for (int nt4 = 0; nt4 < 4; ++nt4) acc[mt][nt4] = (f4)0.f;

    #pragma unroll
    for (int kc = 0; kc < 4; ++kc) {
        s8 a[4];
        #pragma unroll
        for (int mt = 0; mt < 4; ++mt)
            a[mt] = *(const s8*)&x[mt*16 + l16][kc*32 + quad*8];
        #pragma unroll
        for (int nt4 = 0; nt4 < 4; ++nt4) {
            int nt = w*4 + nt4;
            s8 b = *(const s8*)(wcat + (((size_t)nt*4 + kc)*64 + l)*8);
            #pragma unroll
            for (int mt = 0; mt < 4; ++mt)
                acc[mt][nt4] = __builtin_amdgcn_mfma_f32_16x16x32_bf16(a[mt], b, acc[mt][nt4], 0, 0, 0);
        }
    }
    #pragma unroll
    for (int nt4 = 0; nt4 < 4; ++nt4) {
        int col = (w*4 + nt4)*16 + l16;
        float bias = (col < 128) ? b1[col] : 0.f;
        #pragma unroll
        for (int mt = 0; mt < 4; ++mt)
            #pragma unroll
            for (int i = 0; i < 4; ++i) {
                int row = mt*16 + quad*4 + i;
                H1[(long)(n0 + row)*256 + col] = f2b(acc[mt][nt4][i] + bias);
            }
    }
}

// ---------------------------------------------------------------------------
// Edge kernel v6: R8 structure, but NO geometry side-streams — d2/rel computed
// from pos (0.36 MB, L2-hot). Keeps L2 working set ~19 MB so H1 gathers hit L2.
__global__ __launch_bounds__(256, 4) void k_edge6(
    const short* __restrict__ H1,
    const int* __restrict__ rS, const int* __restrict__ cS,
    const float* __restrict__ pos,
    const float* __restrict__ w1c,
    const short* __restrict__ w2p, const float* __restrict__ b2,
    const short* __restrict__ c1p, const float* __restrict__ cb1,
    const float* __restrict__ cw2,
    float* __restrict__ agg, float* __restrict__ upd)
{
    __shared__ short t1[ET][136];
    __shared__ short mm[ET][136];
    __shared__ int   rIs[ET], cIs[ET];
    __shared__ float sred[ET];

    const int tid = threadIdx.x;
    const int l = tid & 63, w = tid >> 6;
    const int l16 = l & 15, quad = l >> 4;
    const int c0 = (2*w)*16 + l16, c1c = (2*w+1)*16 + l16;
    const int half = tid >> 7, ch = tid & 127;
    const int q = tid & 15;          // fixed channel chunk
    const int esub = tid >> 4;       // edge subgroup 0..15

    float wv[8];
    #pragma unroll
    for (int j = 0; j < 8; ++j) wv[j] = w1c[q*8 + j];

    s8 w2f[8], c1f[8];
    #pragma unroll
    for (int kc = 0; kc < 4; ++kc) {
        w2f[kc]     = *(const s8*)(w2p + (((size_t)(2*w)*4 + kc)*64 + l)*8);
        w2f[4 + kc] = *(const s8*)(w2p + (((size_t)(2*w+1)*4 + kc)*64 + l)*8);
        c1f[kc]     = *(const s8*)(c1p + (((size_t)(2*w)*4 + kc)*64 + l)*8);
        c1f[4 + kc] = *(const s8*)(c1p + (((size_t)(2*w+1)*4 + kc)*64 + l)*8);
    }
    const float bia2_0 = b2[c0],  bia2_1 = b2[c1c];
    const float biac_0 = cb1[c0], biac_1 = cb1[c1c];
    const float cw0    = cw2[c0], cw1v   = cw2[c1c];

    // lightweight prefetch: indices + d2 for this thread's 4 edges
    int   pri[4], pci[4];
    float pd2[4];

    auto PREIDX = [&](int T) {
        long eb = (long)T * ET;
        #pragma unroll
        for (int it = 0; it < 4; ++it) {
            int e = esub + 16*it;
            int r = rS[eb + e], c = cS[eb + e];
            pri[it] = r; pci[it] = c;
            float rx = pos[r*3+0] - pos[c*3+0];
            float ry = pos[r*3+1] - pos[c*3+1];
            float rz = pos[r*3+2] - pos[c*3+2];
            pd2[it] = fminf(fmaxf(rx*rx + ry*ry + rz*rz, 1e-6f), 1e6f);
        }
    };

    int t = blockIdx.x;
    if (t < NTILE) PREIDX(t);

    while (t < NTILE) {
        // issue H1 gathers now (coalesced 256B per 16 lanes) — drain at (A)
        s8 va[4], vb[4];
        #pragma unroll
        for (int it = 0; it < 4; ++it) {
            va[it] = *(const s8*)(H1 + (long)pri[it]*256 + q*8);
            vb[it] = *(const s8*)(H1 + (long)pci[it]*256 + 128 + q*8);
        }
        __syncthreads();                 // (A) previous tile fully consumed
        if (tid < ET) sred[tid] = 0.f;
        if (q == 0) {
            #pragma unroll
            for (int it = 0; it < 4; ++it) {
                rIs[esub + 16*it] = pri[it];
                cIs[esub + 16*it] = pci[it];
            }
        }
        // build t1 from gathered regs
        #pragma unroll
        for (int it = 0; it < 4; ++it) {
            int e = esub + 16*it;
            float d2 = pd2[it];
            s8 o;
            #pragma unroll
            for (int j = 0; j < 8; ++j) {
                float v = b2f(va[it][j]) + b2f(vb[it][j]) + d2*wv[j];
                o[j] = f2b(siluf(v));
            }
            *(s8*)&t1[e][q*8] = o;
        }
        __syncthreads();                 // (B) t1 + meta ready

        int tn = t + PBLK;
        if (tn < NTILE) PREIDX(tn);      // cheap loads, drain over stages

        // ---- stage 2: m = silu(t1 @ w2 + b2) -> mm bf16
        {
            f4 acc[4][2];
            #pragma unroll
            for (int mt = 0; mt < 4; ++mt) { acc[mt][0] = (f4)0.f; acc[mt][1] = (f4)0.f; }
            #pragma unroll
            for (int kc = 0; kc < 4; ++kc) {
                #pragma unroll
                for (int mt = 0; mt < 4; ++mt) {
                    s8 a = *(const s8*)&t1[mt*16 + l16][kc*32 + quad*8];
                    acc[mt][0] = __builtin_amdgcn_mfma_f32_16x16x32_bf16(a, w2f[kc],     acc[mt][0], 0, 0, 0);
                    acc[mt][1] = __builtin_amdgcn_mfma_f32_16x16x32_bf16(a, w2f[4 + kc], acc[mt][1], 0, 0, 0);
                }
            }
            #pragma unroll
            for (int mt = 0; mt < 4; ++mt) {
                #pragma unroll
                for (int i = 0; i < 4; ++i) {
                    int row = mt*16 + quad*4 + i;
                    mm[row][c0]  = f2b(siluf(acc[mt][0][i] + bia2_0));
                    mm[row][c1c] = f2b(siluf(acc[mt][1][i] + bia2_1));
                }
            }
        }
        __syncthreads();                 // (C) mm ready

        // ---- stage 3: c1 = silu(mm @ cw1 + cb1); dot cw2 -> sred
        {
            f4 acc[4][2];
            #pragma unroll
            for (int mt = 0; mt < 4; ++mt) { acc[mt][0] = (f4)0.f; acc[mt][1] = (f4)0.f; }
            #pragma unroll
            for (int kc = 0; kc < 4; ++kc) {
                #pragma unroll
                for (int mt = 0; mt < 4; ++mt) {
                    s8 a = *(const s8*)&mm[mt*16 + l16][kc*32 + quad*8];
                    acc[mt][0] = __builtin_amdgcn_mfma_f32_16x16x32_bf16(a, c1f[kc],     acc[mt][0], 0, 0, 0);
                    acc[mt][1] = __builtin_amdgcn_mfma_f32_16x16x32_bf16(a, c1f[4 + kc], acc[mt][1], 0, 0, 0);
                }
            }
            #pragma unroll
            for (int mt = 0; mt < 4; ++mt) {
                #pragma unroll
                for (int i = 0; i < 4; ++i) {
                    float p = siluf(acc[mt][0][i] + biac_0) * cw0
                            + siluf(acc[mt][1][i] + biac_1) * cw1v;
                    p += __shfl_xor(p, 1);
                    p += __shfl_xor(p, 2);
                    p += __shfl_xor(p, 4);
                    p += __shfl_xor(p, 8);
                    if (l16 == 0) {
                        int row = mt*16 + quad*4 + i;
                        atomicAdd(&sred[row], p);
                    }
                }
            }
        }

        // ---- segmented agg reduction over sorted rows (reads mm bf16)
        {
            int e0 = half * 32;
            int cur = rIs[e0];
            float a = 0.f;
            #pragma unroll
            for (int e = e0; e < e0 + 32; ++e) {
                int r = rIs[e];
                if (r != cur) {
                    atomicAdd(&agg[(long)cur*HID + ch], a);
                    a = 0.f; cur = r;
                }
                a += b2f(mm[e][ch]);
            }
            atomicAdd(&agg[(long)cur*HID + ch], a);
        }
        __syncthreads();                 // (D) sred complete

        if (tid < ET) {
            float cwv = fminf(fmaxf(sred[tid], -1.f), 1.f);
            int r = rIs[tid], c = cIs[tid];
            float rx = pos[r*3+0] - pos[c*3+0];
            float ry = pos[r*3+1] - pos[c*3+1];
            float rz = pos[r*3+2] - pos[c*3+2];
            atomicAdd(&upd[r*3+0], cwv*rx);
            atomicAdd(&upd[r*3+1], cwv*ry);
            atomicAdd(&upd[r*3+2], cwv*rz);
        }
        t = tn;
    }
}

// ---------------------------------------------------------------------------
__global__ __launch_bounds__(256) void k_node_mfma(
    short* __restrict__ hb, const float* __restrict__ agg,
    const short* __restrict__ w1p, const float* __restrict__ b1n,
    const short* __restrict__ w2p, const float* __restrict__ b2n,
    const float* __restrict__ lg, const float* __restrict__ lb,
    float* __restrict__ pos, const float* __restrict__ upd,
    const int* __restrict__ rowStart)
{
    __shared__ short x[64][264];
    __shared__ short t1[64][144];
    __shared__ float mus[64], rstds[64];
    float (*hn)[132] = (float (*)[132])&x[0][0];

    const int tid = threadIdx.x;
    const int n0 = blockIdx.x * 64;

    #pragma unroll
    for (int it = 0; it < 4; ++it) {
        int idx = it*256 + tid;
        int e = idx >> 4, q = idx & 15;
        *(int4*)&x[e][q*8] = *(const int4*)(hb + (long)(n0+e)*HID + q*8);
    }
    #pragma unroll
    for (int it = 0; it < 8; ++it) {
        int idx = it*256 + tid;
        int e = idx >> 5, q = idx & 31;
        float4 v = *(const float4*)(agg + (long)(n0+e)*HID + q*4);
        short4 sv;
        sv.x = f2b(v.x); sv.y = f2b(v.y); sv.z = f2b(v.z); sv.w = f2b(v.w);
        *(short4*)&x[e][128 + q*4] = sv;
    }
    __syncthreads();

    const int l = tid & 63, w = tid >> 6;
    const int l16 = l & 15, quad = l >> 4;
    const int nt0 = 2*w, nt1 = 2*w + 1;
    const int c0 = nt0*16 + l16, c1c = nt1*16 + l16;

    {
        f4 acc[4][2];
        #pragma unroll
        for (int mt = 0; mt < 4; ++mt) { acc[mt][0] = (f4)0.f; acc[mt][1] = (f4)0.f; }
        #pragma unroll
        for (int kc = 0; kc < 8; ++kc) {
            s8 b0  = *(const s8*)(w1p + (((size_t)nt0*8 + kc)*64 + l)*8);
            s8 b1f = *(const s8*)(w1p + (((size_t)nt1*8 + kc)*64 + l)*8);
            #pragma unroll
            for (int mt = 0; mt < 4; ++mt) {
                s8 a = *(const s8*)&x[mt*16 + l16][kc*32 + quad*8];
                acc[mt][0] = __builtin_amdgcn_mfma_f32_16x16x32_bf16(a, b0,  acc[mt][0], 0, 0, 0);
                acc[mt][1] = __builtin_amdgcn_mfma_f32_16x16x32_bf16(a, b1f, acc[mt][1], 0, 0, 0);
            }
        }
        float bia0 = b1n[c0], bia1 = b1n[c1c];
        #pragma unroll
        for (int mt = 0; mt < 4; ++mt) {
            #pragma unroll
            for (int i = 0; i < 4; ++i) {
                int row = mt*16 + quad*4 + i;
                t1[row][c0]  = f2b(siluf(acc[mt][0][i] + bia0));
                t1[row][c1c] = f2b(siluf(acc[mt][1][i] + bia1));
            }
        }
    }
    __syncthreads();

    {
        f4 acc[4][2];
        #pragma unroll
        for (int mt = 0; mt < 4; ++mt) { acc[mt][0] = (f4)0.f; acc[mt][1] = (f4)0.f; }
        #pragma unroll
        for (int kc = 0; kc < 4; ++kc) {
            s8 b0  = *(const s8*)(w2p + (((size_t)nt0*4 + kc)*64 + l)*8);
            s8 b1f = *(const s8*)(w2p + (((size_t)nt1*4 + kc)*64 + l)*8);
            #pragma unroll
            for (int mt = 0; mt < 4; ++mt) {
                s8 a = *(const s8*)&t1[mt*16 + l16][kc*32 + quad*8];
                acc[mt][0] = __builtin_amdgcn_mfma_f32_16x16x32_bf16(a, b0,  acc[mt][0], 0, 0, 0);
                acc[mt][1] = __builtin_amdgcn_mfma_f32_16x16x32_bf16(a, b1f, acc[mt][1], 0, 0, 0);
            }
        }
        float bia0 = b2n[c0], bia1 = b2n[c1c];
        __syncthreads();
        #pragma unroll
        for (int mt = 0; mt < 4; ++mt) {
            #pragma unroll
            for (int i = 0; i < 4; ++i) {
                int row = mt*16 + quad*4 + i;
                hn[row][c0]  = acc[mt][0][i] + bia0;
                hn[row][c1c] = acc[mt][1][i] + bia1;
            }
        }
    }
    __syncthreads();

    {
        int r = tid >> 2, part = tid & 3;
        float s = 0.f, q = 0.f;
        #pragma unroll
        for (int j = 0; j < 32; ++j) {
            float v = hn[r][part + 4*j];
            s += v; q += v*v;
        }
        s += __shfl_xor(s, 1); q += __shfl_xor(q, 1);
        s += __shfl_xor(s, 2); q += __shfl_xor(q, 2);
        if (part == 0) {
            float mu = s * (1.0f/HID);
            float var = q * (1.0f/HID) - mu*mu;
            mus[r] = mu;
            rstds[r] = rsqrtf(var + 1e-5f);
        }
    }
    __syncthreads();

    #pragma unroll
    for (int it = 0; it < 32; ++it) {
        int idx = it*256 + tid;
        int r = idx >> 7, c = idx & 127;
        float v = (hn[r][c] - mus[r]) * rstds[r] * lg[c] + lb[c];
        hb[(long)(n0 + r)*HID + c] = f2b(v);
    }
    if (tid < 192) {
        int i = tid / 3, d = tid - i*3;
        int n = n0 + i;
        float dg = (float)(rowStart[n+1] - rowStart[n]);
        pos[n*3+d] += upd[n*3+d] / (dg + 1e-6f);
    }
}

// ---------------------------------------------------------------------------
__global__ void k_head(const short* __restrict__ hb, const float* __restrict__ pos,
                       const float* __restrict__ w1, const float* __restrict__ b1,
                       const float* __restrict__ w2, const float* __restrict__ b2,
                       void* __restrict__ out, const int* __restrict__ flags)
{
    __shared__ float hs[4][HID];
    __shared__ float t[4][64];
    const int tid = threadIdx.x;
    const int n0 = blockIdx.x * 4;
    for (int i = tid; i < 4*HID; i += 256)
        hs[i >> 7][i & 127] = b2f(hb[(long)n0*HID + i]);
    __syncthreads();
    const int s = tid >> 6, c = tid & 63;
    float acc = b1[c];
    for (int k4 = 0; k4 < 32; ++k4) {
        int k = k4*4;
        float wa = w1[(k+0)*64 + c];
        float wb = w1[(k+1)*64 + c];
        float wc = w1[(k+2)*64 + c];
        float wd = w1[(k+3)*64 + c];
        float4 v = *(const float4*)&hs[s][k];
        acc += v.x*wa + v.y*wb + v.z*wc + v.w*wd;
    }
    t[s][c] = siluf(acc);
    __syncthreads();
    if (c < 3) {
        float a2 = b2[c];
        #pragma unroll
        for (int k = 0; k < 64; ++k) a2 += t[s][k] * w2[k*3 + c];
        int n = n0 + s;
        float v = pos[n*3+c] + a2;
        if (flags[0]) ((__hip_bfloat16*)out)[n*3+c] = __float2bfloat16(v);
        else          ((float*)out)[n*3+c] = v;
    }
}

// ---------------------------------------------------------------------------
extern "C" void kernel_launch(void* const* d_in, const int* in_sizes, int n_in,
                              void* d_out, int out_size, void* d_ws, size_t ws_size,
                              hipStream_t stream)
{
    (void)in_sizes; (void)n_in; (void)out_size; (void)ws_size;

    int* flags = (int*)d_ws;
    float* base = (float*)d_ws;
    size_t off = 64;
    auto alloc = [&](size_t n) { float* p = base + off; off += (n + 63) & ~63ull; return p; };

    static const int aidx[24] = {0,1,3,4,5,6,7,8,9,10,11,12,13,14,15,16,17,18,19,20,21,22,23,24};
    static const int alen[24] = {
        BB*LAT, NN*AF, NA*3, LAT*HID, HID, AF*HID, HID,
        NL*257*HID, NL*HID, NL*HID*HID, NL*HID,
        NL*256*HID, NL*HID, NL*HID*HID, NL*HID,
        NL*HID*HID, NL*HID, NL*HID, NL*HID, NL*HID,
        HID*64, 64, 64*3, 3
    };
    CvtDesc cd;
    float* fp[24];
    for (int a = 0; a < 24; ++a) {
        fp[a] = alloc((size_t)alen[a]);
        cd.src[a] = d_in[aidx[a]];
        cd.dst[a] = fp[a];
        cd.len[a] = alen[a];
    }
    float* agg = alloc((size_t)NN*HID);
    float* hz  = alloc((size_t)BB*HID);
    float* pos = alloc((size_t)NN*3);
    float* upd = alloc((size_t)NN*3);
    short* hb  = (short*)alloc((size_t)NN*HID/2);
    short* H1  = (short*)alloc((size_t)NN*256/2);
    short* wcatp = (short*)alloc((size_t)NL*32768/2);
    short* w2p = (short*)alloc((size_t)NL*16384/2);
    short* c1p = (short*)alloc((size_t)NL*16384/2);
    short* nw1p = (short*)alloc((size_t)NL*32768/2);
    short* nw2p = (short*)alloc((size_t)NL*16384/2);
    int* cnt      = (int*)alloc((size_t)NN);
    int* rowStart = (int*)alloc((size_t)NN + 1);
    int* cursor   = (int*)alloc((size_t)NN);
    int* rS       = (int*)alloc((size_t)NE);
    int* cS       = (int*)alloc((size_t)NE);
    const int* eidx = (const int*)d_in[2];

    k_detect<<<1, 256, 0, stream>>>((const unsigned short*)d_in[0],
                                    (const unsigned int*)d_in[2], flags);
    k_convert<<<dim3((NN*AF + 255)/256, 24), 256, 0, stream>>>(cd, flags);

    PackJobs pj;
    for (int l = 0; l < NL; ++l) {
        int b5 = l*5;
        pj.src[b5+0] = fp[7]  + (size_t)l*257*HID; pj.dst[b5+0] = wcatp + (size_t)l*32768; pj.K[b5+0] = 256; pj.mode[b5+0] = 1;
        pj.src[b5+1] = fp[9]  + (size_t)l*HID*HID; pj.dst[b5+1] = w2p   + (size_t)l*16384; pj.K[b5+1] = 128; pj.mode[b5+1] = 0;
        pj.src[b5+2] = fp[15] + (size_t)l*HID*HID; pj.dst[b5+2] = c1p   + (size_t)l*16384; pj.K[b5+2] = 128; pj.mode[b5+2] = 0;
        pj.src[b5+3] = fp[11] + (size_t)l*256*HID; pj.dst[b5+3] = nw1p  + (size_t)l*32768; pj.K[b5+3] = 256; pj.mode[b5+3] = 0;
        pj.src[b5+4] = fp[13] + (size_t)l*HID*HID; pj.dst[b5+4] = nw2p  + (size_t)l*16384; pj.K[b5+4] = 128; pj.mode[b5+4] = 0;
    }
    k_packall<<<dim3(128, 10), 256, 0, stream>>>(pj);

    // counting sort edges by row
    k_zero_cnt<<<(NN + 255)/256, 256, 0, stream>>>(cnt);
    k_hist<<<(NE + 255)/256, 256, 0, stream>>>(eidx, flags, cnt);
    k_scan<<<1, 1024, 0, stream>>>(cnt, rowStart, cursor);
    k_scatter<<<(NE + 255)/256, 256, 0, stream>>>(eidx, flags, cursor, rS, cS);

    k_hz<<<BB, HID, 0, stream>>>(fp[0], fp[3], fp[4], hz);
    k_init2<<<NN, HID, 0, stream>>>(hz, fp[1], fp[5], fp[6], fp[2], pos, hb);

    for (int l = 0; l < NL; ++l) {
        k_pre<<<NN/64, 256, 0, stream>>>(hb, wcatp + (size_t)l*32768,
                                         fp[8] + (size_t)l*HID, H1, agg, upd);
        k_edge6<<<PBLK, 256, 0, stream>>>(H1, rS, cS, pos,
            fp[7] + (size_t)l*257*HID + 256*HID,       // w1c (d2 row, f32)
            w2p + (size_t)l*16384, fp[10] + (size_t)l*HID,
            c1p + (size_t)l*16384, fp[16] + (size_t)l*HID,
            fp[17] + (size_t)l*HID,
            agg, upd);
        k_node_mfma<<<NN/64, 256, 0, stream>>>(hb, agg,
            nw1p + (size_t)l*32768, fp[12] + (size_t)l*HID,
            nw2p + (size_t)l*16384, fp[14] + (size_t)l*HID,
            fp[18] + (size_t)l*HID, fp[19] + (size_t)l*HID,
            pos, upd, rowStart);
    }
    k_head<<<NN/4, 256, 0, stream>>>(hb, pos, fp[20], fp[21], fp[22], fp[23],
                                     d_out, flags);
}

// Round 11
// 679.178 us; speedup vs baseline: 1.3930x; 1.0694x over previous
//
#include <hip/hip_runtime.h>
#include <hip/hip_bf16.h>

#define BB 512
#define NA 58
#define LAT 64
#define HID 128
#define AF 10
#define NL 2
#define NN (BB*NA)      // 29696
#define NE (NN*16)      // 475136
#define ET 64           // edges per tile
#define NTILE (NE/ET)   // 7424
#define PBLK 768        // persistent blocks (3 per CU)

typedef __attribute__((ext_vector_type(8))) short s8;
typedef __attribute__((ext_vector_type(4))) float f4;

struct CvtDesc {
    const void* src[24];
    float*      dst[24];
    int         len[24];
};

struct PackJobs {
    const float* src[10];
    short*       dst[10];
    int          K[10];
    int          mode[10];
};

__device__ __forceinline__ float siluf(float x) {
    return x * __builtin_amdgcn_rcpf(1.0f + __expf(-x));
}

__device__ __forceinline__ short f2b(float x) {
    __hip_bfloat16 b = __float2bfloat16(x);
    return *(short*)&b;
}

__device__ __forceinline__ float b2f(short s) {
    return __uint_as_float(((unsigned int)(unsigned short)s) << 16);
}

// ---------------------------------------------------------------------------
__global__ void k_detect(const unsigned short* __restrict__ z16,
                         const unsigned int* __restrict__ e32,
                         int* __restrict__ flags) {
    __shared__ int sbf, si64;
    if (threadIdx.x == 0) { sbf = 0; si64 = 0; }
    __syncthreads();
    int c1 = 0, c2 = 0;
    for (int i = threadIdx.x; i < 1024; i += 256) {
        unsigned short v = z16[2*i];
        int e = (v >> 7) & 0xFF;
        if (e >= 100 && e <= 140) c1++;
        if (e32[2*i + 1] == 0u) c2++;
    }
    atomicAdd(&sbf, c1);
    atomicAdd(&si64, c2);
    __syncthreads();
    if (threadIdx.x == 0) {
        flags[0] = (sbf  > 600) ? 1 : 0;
        flags[1] = (si64 > 600) ? 1 : 0;
    }
}

__global__ void k_convert(CvtDesc d, const int* __restrict__ flags) {
    int a = blockIdx.y;
    int i = blockIdx.x * blockDim.x + threadIdx.x;
    int n = d.len[a];
    if (i >= n) return;
    if (flags[0]) {
        d.dst[a][i] = __bfloat162float(((const __hip_bfloat16*)d.src[a])[i]);
    } else {
        d.dst[a][i] = ((const float*)d.src[a])[i];
    }
}

__global__ void k_packall(PackJobs pj) {
    int j = blockIdx.y;
    int idx = blockIdx.x * 256 + threadIdx.x;
    const float* w = pj.src[j];
    short* o = pj.dst[j];
    if (pj.mode[j] == 0) {
        int K = pj.K[j];
        if (idx >= 128*K) return;
        int jj = idx & 7;
        int l  = (idx >> 3) & 63;
        int rest = idx >> 9;
        int KC = K >> 5;
        int kc = rest % KC;
        int nt = rest / KC;
        int n = nt*16 + (l & 15);
        int k = kc*32 + (l >> 4)*8 + jj;
        o[idx] = f2b(w[k*128 + n]);
    } else {
        if (idx >= 32768) return;
        int jj = idx & 7;
        int l  = (idx >> 3) & 63;
        int rest = idx >> 9;
        int kc = rest & 3;
        int nt = rest >> 2;
        int n = nt*16 + (l & 15);
        int k = kc*32 + (l >> 4)*8 + jj;
        float v = (n < 128) ? w[k*128 + n] : w[(128 + k)*128 + (n - 128)];
        o[idx] = f2b(v);
    }
}

// ---------------------------------------------------------------------------
__global__ void k_hist(const int* __restrict__ eidx, const int* __restrict__ flags,
                       int* __restrict__ cnt) {
    int e = blockIdx.x * 256 + threadIdx.x;
    if (e >= NE) return;
    int is64 = flags[1];
    int r = eidx[is64 ? 2*(long)e : (long)e];
    atomicAdd(&cnt[r], 1);
}

__global__ __launch_bounds__(1024) void k_scan(const int* __restrict__ cnt,
                                               int* __restrict__ rowStart,
                                               int* __restrict__ cursor) {
    __shared__ int part[1024];
    int t = threadIdx.x;
    int base = t * 29;                    // NN == 1024*29
    int loc[29];
    int s = 0;
    #pragma unroll
    for (int i = 0; i < 29; ++i) { loc[i] = s; s += cnt[base + i]; }
    part[t] = s;
    __syncthreads();
    for (int d = 1; d < 1024; d <<= 1) {
        int v = (t >= d) ? part[t - d] : 0;
        __syncthreads();
        part[t] += v;
        __syncthreads();
    }
    int pre = (t == 0) ? 0 : part[t - 1];
    #pragma unroll
    for (int i = 0; i < 29; ++i) {
        int v = pre + loc[i];
        rowStart[base + i] = v;
        cursor[base + i] = v;
    }
    if (t == 1023) rowStart[NN] = pre + s;
}

__global__ void k_scatter(const int* __restrict__ eidx, const int* __restrict__ flags,
                          int* __restrict__ cursor,
                          int* __restrict__ rS, int* __restrict__ cS) {
    int e = blockIdx.x * 256 + threadIdx.x;
    if (e >= NE) return;
    int is64 = flags[1];
    long ge = e, gc = (long)e + NE;
    int r = eidx[is64 ? 2*ge : ge];
    int c = eidx[is64 ? 2*gc : gc];
    int p = atomicAdd(&cursor[r], 1);
    rS[p] = r; cS[p] = c;
}

// ---------------------------------------------------------------------------
__global__ void k_hz(const float* __restrict__ z, const float* __restrict__ lw,
                     const float* __restrict__ lb, float* __restrict__ hz) {
    __shared__ float zs[LAT];
    int b = blockIdx.x;
    int c = threadIdx.x;
    if (c < LAT) zs[c] = z[b*LAT + c];
    __syncthreads();
    float acc = lb[c];
    #pragma unroll
    for (int k = 0; k < LAT; ++k) acc += zs[k] * lw[k*HID + c];
    hz[b*HID + c] = acc;
}

__global__ void k_init2(const float* __restrict__ hz, const float* __restrict__ at,
                        const float* __restrict__ aw, const float* __restrict__ ab,
                        const float* __restrict__ ic,
                        float* __restrict__ pos, short* __restrict__ hb) {
    __shared__ float ats[AF];
    int n = blockIdx.x;
    int c = threadIdx.x;
    int b = n / NA;
    if (c < AF) ats[c] = at[n*AF + c];
    __syncthreads();
    float acc = hz[b*HID + c] + ab[c];
    #pragma unroll
    for (int f = 0; f < AF; ++f) acc += ats[f] * aw[f*HID + c];
    hb[(long)n*HID + c] = f2b(acc);
    if (c < 3) {
        int a = n % NA;
        pos[n*3 + c] = ic[a*3 + c];
    }
}

// ---------------------------------------------------------------------------
// H1 = hb @ [w1a|w1b] (+ b1 on a-half) -> [NN][256] bf16.  Also zeros agg/upd.
__global__ __launch_bounds__(256) void k_pre(
    const short* __restrict__ hb, const short* __restrict__ wcat,
    const float* __restrict__ b1, short* __restrict__ H1,
    float* __restrict__ agg, float* __restrict__ upd)
{
    __shared__ short x[64][136];
    const int tid = threadIdx.x;
    const int n0 = blockIdx.x * 64;

    {
        long base = (long)blockIdx.x*256 + tid;
        f4* a4 = (f4*)agg;
        for (long j = base; j < (long)NN*HID/4; j += (long)gridDim.x*256) a4[j] = (f4)0.f;
        if (base < NN*3) upd[base] = 0.f;
    }

    #pragma unroll
    for (int it = 0; it < 4; ++it) {
        int idx = it*256 + tid;
        int e = idx >> 4, q = idx & 15;
        *(int4*)&x[e][q*8] = *(const int4*)(hb + (long)(n0+e)*HID + q*8);
    }
    __syncthreads();

    const int l = tid & 63, w = tid >> 6;
    const int l16 = l & 15, quad = l >> 4;

    f4 acc[4][4];
    #pragma unroll
    for (int mt = 0; mt < 4; ++mt)
        #pragma unroll
        for (int nt4 = 0; nt4 < 4; ++nt4) acc[mt][nt4] = (f4)0.f;

    #pragma unroll
    for (int kc = 0; kc < 4; ++kc) {
        s8 a[4];
        #pragma unroll
        for (int mt = 0; mt < 4; ++mt)
            a[mt] = *(const s8*)&x[mt*16 + l16][kc*32 + quad*8];
        #pragma unroll
        for (int nt4 = 0; nt4 < 4; ++nt4) {
            int nt = w*4 + nt4;
            s8 b = *(const s8*)(wcat + (((size_t)nt*4 + kc)*64 + l)*8);
            #pragma unroll
            for (int mt = 0; mt < 4; ++mt)
                acc[mt][nt4] = __builtin_amdgcn_mfma_f32_16x16x32_bf16(a[mt], b, acc[mt][nt4], 0, 0, 0);
        }
    }
    #pragma unroll
    for (int nt4 = 0; nt4 < 4; ++nt4) {
        int col = (w*4 + nt4)*16 + l16;
        float bias = (col < 128) ? b1[col] : 0.f;
        #pragma unroll
        for (int mt = 0; mt < 4; ++mt)
            #pragma unroll
            for (int i = 0; i < 4; ++i) {
                int row = mt*16 + quad*4 + i;
                H1[(long)(n0 + row)*256 + col] = f2b(acc[mt][nt4][i] + bias);
            }
    }
}

// ---------------------------------------------------------------------------
// Edge kernel v7: R5's memory discipline (gathers loaded AFTER the barrier,
// consumed immediately — no vector state or vmcnt across barriers) + register
// meta-prefetch (12 VGPRs) for a 4-barrier tile. 3 blocks/CU (proven no-spill).
__global__ __launch_bounds__(256, 3) void k_edge7(
    const short* __restrict__ H1,
    const int* __restrict__ rS, const int* __restrict__ cS,
    const float* __restrict__ pos,
    const float* __restrict__ w1c,
    const short* __restrict__ w2p, const float* __restrict__ b2,
    const short* __restrict__ c1p, const float* __restrict__ cb1,
    const float* __restrict__ cw2,
    float* __restrict__ agg, float* __restrict__ upd)
{
    __shared__ short t1[ET][136];
    __shared__ short mm[ET][136];
    __shared__ int   rIs[ET], cIs[ET];
    __shared__ float sred[ET];

    const int tid = threadIdx.x;
    const int l = tid & 63, w = tid >> 6;
    const int l16 = l & 15, quad = l >> 4;
    const int c0 = (2*w)*16 + l16, c1c = (2*w+1)*16 + l16;
    const int half = tid >> 7, ch = tid & 127;
    const int q = tid & 15;          // fixed channel chunk
    const int esub = tid >> 4;       // edge subgroup 0..15

    float wv[8];
    #pragma unroll
    for (int j = 0; j < 8; ++j) wv[j] = w1c[q*8 + j];

    s8 w2f[8], c1f[8];
    #pragma unroll
    for (int kc = 0; kc < 4; ++kc) {
        w2f[kc]     = *(const s8*)(w2p + (((size_t)(2*w)*4 + kc)*64 + l)*8);
        w2f[4 + kc] = *(const s8*)(w2p + (((size_t)(2*w+1)*4 + kc)*64 + l)*8);
        c1f[kc]     = *(const s8*)(c1p + (((size_t)(2*w)*4 + kc)*64 + l)*8);
        c1f[4 + kc] = *(const s8*)(c1p + (((size_t)(2*w+1)*4 + kc)*64 + l)*8);
    }
    const float bia2_0 = b2[c0],  bia2_1 = b2[c1c];
    const float biac_0 = cb1[c0], biac_1 = cb1[c1c];
    const float cw0    = cw2[c0], cw1v   = cw2[c1c];

    // meta prefetch: indices + d2 for this thread's 4 edges (12 VGPRs)
    int   pri[4], pci[4];
    float pd2[4];

    auto PREIDX = [&](int T) {
        long eb = (long)T * ET;
        #pragma unroll
        for (int it = 0; it < 4; ++it) {
            int e = esub + 16*it;
            int r = rS[eb + e], c = cS[eb + e];
            pri[it] = r; pci[it] = c;
            float rx = pos[r*3+0] - pos[c*3+0];
            float ry = pos[r*3+1] - pos[c*3+1];
            float rz = pos[r*3+2] - pos[c*3+2];
            pd2[it] = fminf(fmaxf(rx*rx + ry*ry + rz*rz, 1e-6f), 1e6f);
        }
    };

    int t = blockIdx.x;
    if (t < NTILE) PREIDX(t);

    while (t < NTILE) {
        __syncthreads();                 // (A) previous tile fully consumed
        if (tid < ET) sred[tid] = 0.f;
        if (q == 0) {
            #pragma unroll
            for (int it = 0; it < 4; ++it) {
                rIs[esub + 16*it] = pri[it];
                cIs[esub + 16*it] = pci[it];
            }
        }
        // gather H1 AFTER the barrier; loads are issued together and consumed
        // immediately (no cross-barrier vector state -> no spill)
        #pragma unroll
        for (int it = 0; it < 4; ++it) {
            s8 va = *(const s8*)(H1 + (long)pri[it]*256 + q*8);
            s8 vb = *(const s8*)(H1 + (long)pci[it]*256 + 128 + q*8);
            float d2 = pd2[it];
            s8 o;
            #pragma unroll
            for (int j = 0; j < 8; ++j) {
                float v = b2f(va[j]) + b2f(vb[j]) + d2*wv[j];
                o[j] = f2b(siluf(v));
            }
            *(s8*)&t1[esub + 16*it][q*8] = o;
        }
        __syncthreads();                 // (B) t1 + meta ready

        int tn = t + PBLK;
        if (tn < NTILE) PREIDX(tn);      // 12 light loads drain over stages

        // ---- stage 2: m = silu(t1 @ w2 + b2) -> mm bf16
        {
            f4 acc[4][2];
            #pragma unroll
            for (int mt = 0; mt < 4; ++mt) { acc[mt][0] = (f4)0.f; acc[mt][1] = (f4)0.f; }
            #pragma unroll
            for (int kc = 0; kc < 4; ++kc) {
                #pragma unroll
                for (int mt = 0; mt < 4; ++mt) {
                    s8 a = *(const s8*)&t1[mt*16 + l16][kc*32 + quad*8];
                    acc[mt][0] = __builtin_amdgcn_mfma_f32_16x16x32_bf16(a, w2f[kc],     acc[mt][0], 0, 0, 0);
                    acc[mt][1] = __builtin_amdgcn_mfma_f32_16x16x32_bf16(a, w2f[4 + kc], acc[mt][1], 0, 0, 0);
                }
            }
            #pragma unroll
            for (int mt = 0; mt < 4; ++mt) {
                #pragma unroll
                for (int i = 0; i < 4; ++i) {
                    int row = mt*16 + quad*4 + i;
                    mm[row][c0]  = f2b(siluf(acc[mt][0][i] + bia2_0));
                    mm[row][c1c] = f2b(siluf(acc[mt][1][i] + bia2_1));
                }
            }
        }
        __syncthreads();                 // (C) mm ready

        // ---- stage 3: c1 = silu(mm @ cw1 + cb1); dot cw2 -> sred
        {
            f4 acc[4][2];
            #pragma unroll
            for (int mt = 0; mt < 4; ++mt) { acc[mt][0] = (f4)0.f; acc[mt][1] = (f4)0.f; }
            #pragma unroll
            for (int kc = 0; kc < 4; ++kc) {
                #pragma unroll
                for (int mt = 0; mt < 4; ++mt) {
                    s8 a = *(const s8*)&mm[mt*16 + l16][kc*32 + quad*8];
                    acc[mt][0] = __builtin_amdgcn_mfma_f32_16x16x32_bf16(a, c1f[kc],     acc[mt][0], 0, 0, 0);
                    acc[mt][1] = __builtin_amdgcn_mfma_f32_16x16x32_bf16(a, c1f[4 + kc], acc[mt][1], 0, 0, 0);
                }
            }
            #pragma unroll
            for (int mt = 0; mt < 4; ++mt) {
                #pragma unroll
                for (int i = 0; i < 4; ++i) {
                    float p = siluf(acc[mt][0][i] + biac_0) * cw0
                            + siluf(acc[mt][1][i] + biac_1) * cw1v;
                    p += __shfl_xor(p, 1);
                    p += __shfl_xor(p, 2);
                    p += __shfl_xor(p, 4);
                    p += __shfl_xor(p, 8);
                    if (l16 == 0) {
                        int row = mt*16 + quad*4 + i;
                        atomicAdd(&sred[row], p);
                    }
                }
            }
        }

        // ---- segmented agg reduction over sorted rows (reads mm bf16)
        {
            int e0 = half * 32;
            int cur = rIs[e0];
            float a = 0.f;
            #pragma unroll
            for (int e = e0; e < e0 + 32; ++e) {
                int r = rIs[e];
                if (r != cur) {
                    atomicAdd(&agg[(long)cur*HID + ch], a);
                    a = 0.f; cur = r;
                }
                a += b2f(mm[e][ch]);
            }
            atomicAdd(&agg[(long)cur*HID + ch], a);
        }
        __syncthreads();                 // (D) sred complete

        if (tid < ET) {
            float cwv = fminf(fmaxf(sred[tid], -1.f), 1.f);
            int r = rIs[tid], c = cIs[tid];
            float rx = pos[r*3+0] - pos[c*3+0];
            float ry = pos[r*3+1] - pos[c*3+1];
            float rz = pos[r*3+2] - pos[c*3+2];
            atomicAdd(&upd[r*3+0], cwv*rx);
            atomicAdd(&upd[r*3+1], cwv*ry);
            atomicAdd(&upd[r*3+2], cwv*rz);
        }
        t = tn;
    }
}

// ---------------------------------------------------------------------------
__global__ __launch_bounds__(256) void k_node_mfma(
    short* __restrict__ hb, const float* __restrict__ agg,
    const short* __restrict__ w1p, const float* __restrict__ b1n,
    const short* __restrict__ w2p, const float* __restrict__ b2n,
    const float* __restrict__ lg, const float* __restrict__ lb,
    float* __restrict__ pos, const float* __restrict__ upd,
    const int* __restrict__ rowStart)
{
    __shared__ short x[64][264];
    __shared__ short t1[64][144];
    __shared__ float mus[64], rstds[64];
    float (*hn)[132] = (float (*)[132])&x[0][0];

    const int tid = threadIdx.x;
    const int n0 = blockIdx.x * 64;

    #pragma unroll
    for (int it = 0; it < 4; ++it) {
        int idx = it*256 + tid;
        int e = idx >> 4, q = idx & 15;
        *(int4*)&x[e][q*8] = *(const int4*)(hb + (long)(n0+e)*HID + q*8);
    }
    #pragma unroll
    for (int it = 0; it < 8; ++it) {
        int idx = it*256 + tid;
        int e = idx >> 5, q = idx & 31;
        float4 v = *(const float4*)(agg + (long)(n0+e)*HID + q*4);
        short4 sv;
        sv.x = f2b(v.x); sv.y = f2b(v.y); sv.z = f2b(v.z); sv.w = f2b(v.w);
        *(short4*)&x[e][128 + q*4] = sv;
    }
    __syncthreads();

    const int l = tid & 63, w = tid >> 6;
    const int l16 = l & 15, quad = l >> 4;
    const int nt0 = 2*w, nt1 = 2*w + 1;
    const int c0 = nt0*16 + l16, c1c = nt1*16 + l16;

    {
        f4 acc[4][2];
        #pragma unroll
        for (int mt = 0; mt < 4; ++mt) { acc[mt][0] = (f4)0.f; acc[mt][1] = (f4)0.f; }
        #pragma unroll
        for (int kc = 0; kc < 8; ++kc) {
            s8 b0  = *(const s8*)(w1p + (((size_t)nt0*8 + kc)*64 + l)*8);
            s8 b1f = *(const s8*)(w1p + (((size_t)nt1*8 + kc)*64 + l)*8);
            #pragma unroll
            for (int mt = 0; mt < 4; ++mt) {
                s8 a = *(const s8*)&x[mt*16 + l16][kc*32 + quad*8];
                acc[mt][0] = __builtin_amdgcn_mfma_f32_16x16x32_bf16(a, b0,  acc[mt][0], 0, 0, 0);
                acc[mt][1] = __builtin_amdgcn_mfma_f32_16x16x32_bf16(a, b1f, acc[mt][1], 0, 0, 0);
            }
        }
        float bia0 = b1n[c0], bia1 = b1n[c1c];
        #pragma unroll
        for (int mt = 0; mt < 4; ++mt) {
            #pragma unroll
            for (int i = 0; i < 4; ++i) {
                int row = mt*16 + quad*4 + i;
                t1[row][c0]  = f2b(siluf(acc[mt][0][i] + bia0));
                t1[row][c1c] = f2b(siluf(acc[mt][1][i] + bia1));
            }
        }
    }
    __syncthreads();

    {
        f4 acc[4][2];
        #pragma unroll
        for (int mt = 0; mt < 4; ++mt) { acc[mt][0] = (f4)0.f; acc[mt][1] = (f4)0.f; }
        #pragma unroll
        for (int kc = 0; kc < 4; ++kc) {
            s8 b0  = *(const s8*)(w2p + (((size_t)nt0*4 + kc)*64 + l)*8);
            s8 b1f = *(const s8*)(w2p + (((size_t)nt1*4 + kc)*64 + l)*8);
            #pragma unroll
            for (int mt = 0; mt < 4; ++mt) {
                s8 a = *(const s8*)&t1[mt*16 + l16][kc*32 + quad*8];
                acc[mt][0] = __builtin_amdgcn_mfma_f32_16x16x32_bf16(a, b0,  acc[mt][0], 0, 0, 0);
                acc[mt][1] = __builtin_amdgcn_mfma_f32_16x16x32_bf16(a, b1f, acc[mt][1], 0, 0, 0);
            }
        }
        float bia0 = b2n[c0], bia1 = b2n[c1c];
        __syncthreads();
        #pragma unroll
        for (int mt = 0; mt < 4; ++mt) {
            #pragma unroll
            for (int i = 0; i < 4; ++i) {
                int row = mt*16 + quad*4 + i;
                hn[row][c0]  = acc[mt][0][i] + bia0;
                hn[row][c1c] = acc[mt][1][i] + bia1;
            }
        }
    }
    __syncthreads();

    {
        int r = tid >> 2, part = tid & 3;
        float s = 0.f, q = 0.f;
        #pragma unroll
        for (int j = 0; j < 32; ++j) {
            float v = hn[r][part + 4*j];
            s += v; q += v*v;
        }
        s += __shfl_xor(s, 1); q += __shfl_xor(q, 1);
        s += __shfl_xor(s, 2); q += __shfl_xor(q, 2);
        if (part == 0) {
            float mu = s * (1.0f/HID);
            float var = q * (1.0f/HID) - mu*mu;
            mus[r] = mu;
            rstds[r] = rsqrtf(var + 1e-5f);
        }
    }
    __syncthreads();

    #pragma unroll
    for (int it = 0; it < 32; ++it) {
        int idx = it*256 + tid;
        int r = idx >> 7, c = idx & 127;
        float v = (hn[r][c] - mus[r]) * rstds[r] * lg[c] + lb[c];
        hb[(long)(n0 + r)*HID + c] = f2b(v);
    }
    if (tid < 192) {
        int i = tid / 3, d = tid - i*3;
        int n = n0 + i;
        float dg = (float)(rowStart[n+1] - rowStart[n]);
        pos[n*3+d] += upd[n*3+d] / (dg + 1e-6f);
    }
}

// ---------------------------------------------------------------------------
__global__ void k_head(const short* __restrict__ hb, const float* __restrict__ pos,
                       const float* __restrict__ w1, const float* __restrict__ b1,
                       const float* __restrict__ w2, const float* __restrict__ b2,
                       void* __restrict__ out, const int* __restrict__ flags)
{
    __shared__ float hs[4][HID];
    __shared__ float t[4][64];
    const int tid = threadIdx.x;
    const int n0 = blockIdx.x * 4;
    for (int i = tid; i < 4*HID; i += 256)
        hs[i >> 7][i & 127] = b2f(hb[(long)n0*HID + i]);
    __syncthreads();
    const int s = tid >> 6, c = tid & 63;
    float acc = b1[c];
    for (int k4 = 0; k4 < 32; ++k4) {
        int k = k4*4;
        float wa = w1[(k+0)*64 + c];
        float wb = w1[(k+1)*64 + c];
        float wc = w1[(k+2)*64 + c];
        float wd = w1[(k+3)*64 + c];
        float4 v = *(const float4*)&hs[s][k];
        acc += v.x*wa + v.y*wb + v.z*wc + v.w*wd;
    }
    t[s][c] = siluf(acc);
    __syncthreads();
    if (c < 3) {
        float a2 = b2[c];
        #pragma unroll
        for (int k = 0; k < 64; ++k) a2 += t[s][k] * w2[k*3 + c];
        int n = n0 + s;
        float v = pos[n*3+c] + a2;
        if (flags[0]) ((__hip_bfloat16*)out)[n*3+c] = __float2bfloat16(v);
        else          ((float*)out)[n*3+c] = v;
    }
}

// ---------------------------------------------------------------------------
extern "C" void kernel_launch(void* const* d_in, const int* in_sizes, int n_in,
                              void* d_out, int out_size, void* d_ws, size_t ws_size,
                              hipStream_t stream)
{
    (void)in_sizes; (void)n_in; (void)out_size; (void)ws_size;

    int* flags = (int*)d_ws;
    float* base = (float*)d_ws;
    size_t off = 64;
    auto alloc = [&](size_t n) { float* p = base + off; off += (n + 63) & ~63ull; return p; };

    static const int aidx[24] = {0,1,3,4,5,6,7,8,9,10,11,12,13,14,15,16,17,18,19,20,21,22,23,24};
    static const int alen[24] = {
        BB*LAT, NN*AF, NA*3, LAT*HID, HID, AF*HID, HID,
        NL*257*HID, NL*HID, NL*HID*HID, NL*HID,
        NL*256*HID, NL*HID, NL*HID*HID, NL*HID,
        NL*HID*HID, NL*HID, NL*HID, NL*HID, NL*HID,
        HID*64, 64, 64*3, 3
    };
    CvtDesc cd;
    float* fp[24];
    for (int a = 0; a < 24; ++a) {
        fp[a] = alloc((size_t)alen[a]);
        cd.src[a] = d_in[aidx[a]];
        cd.dst[a] = fp[a];
        cd.len[a] = alen[a];
    }
    float* agg = alloc((size_t)NN*HID);
    float* hz  = alloc((size_t)BB*HID);
    float* pos = alloc((size_t)NN*3);
    float* upd = alloc((size_t)NN*3);
    short* hb  = (short*)alloc((size_t)NN*HID/2);
    short* H1  = (short*)alloc((size_t)NN*256/2);
    short* wcatp = (short*)alloc((size_t)NL*32768/2);
    short* w2p = (short*)alloc((size_t)NL*16384/2);
    short* c1p = (short*)alloc((size_t)NL*16384/2);
    short* nw1p = (short*)alloc((size_t)NL*32768/2);
    short* nw2p = (short*)alloc((size_t)NL*16384/2);
    int* cnt      = (int*)alloc((size_t)NN);
    int* rowStart = (int*)alloc((size_t)NN + 1);
    int* cursor   = (int*)alloc((size_t)NN);
    int* rS       = (int*)alloc((size_t)NE);
    int* cS       = (int*)alloc((size_t)NE);
    const int* eidx = (const int*)d_in[2];

    k_detect<<<1, 256, 0, stream>>>((const unsigned short*)d_in[0],
                                    (const unsigned int*)d_in[2], flags);
    k_convert<<<dim3((NN*AF + 255)/256, 24), 256, 0, stream>>>(cd, flags);

    PackJobs pj;
    for (int l = 0; l < NL; ++l) {
        int b5 = l*5;
        pj.src[b5+0] = fp[7]  + (size_t)l*257*HID; pj.dst[b5+0] = wcatp + (size_t)l*32768; pj.K[b5+0] = 256; pj.mode[b5+0] = 1;
        pj.src[b5+1] = fp[9]  + (size_t)l*HID*HID; pj.dst[b5+1] = w2p   + (size_t)l*16384; pj.K[b5+1] = 128; pj.mode[b5+1] = 0;
        pj.src[b5+2] = fp[15] + (size_t)l*HID*HID; pj.dst[b5+2] = c1p   + (size_t)l*16384; pj.K[b5+2] = 128; pj.mode[b5+2] = 0;
        pj.src[b5+3] = fp[11] + (size_t)l*256*HID; pj.dst[b5+3] = nw1p  + (size_t)l*32768; pj.K[b5+3] = 256; pj.mode[b5+3] = 0;
        pj.src[b5+4] = fp[13] + (size_t)l*HID*HID; pj.dst[b5+4] = nw2p  + (size_t)l*16384; pj.K[b5+4] = 128; pj.mode[b5+4] = 0;
    }
    k_packall<<<dim3(128, 10), 256, 0, stream>>>(pj);

    // counting sort edges by row
    hipMemsetAsync(cnt, 0, (size_t)NN*sizeof(int), stream);
    k_hist<<<(NE + 255)/256, 256, 0, stream>>>(eidx, flags, cnt);
    k_scan<<<1, 1024, 0, stream>>>(cnt, rowStart, cursor);
    k_scatter<<<(NE + 255)/256, 256, 0, stream>>>(eidx, flags, cursor, rS, cS);

    k_hz<<<BB, HID, 0, stream>>>(fp[0], fp[3], fp[4], hz);
    k_init2<<<NN, HID, 0, stream>>>(hz, fp[1], fp[5], fp[6], fp[2], pos, hb);

    for (int l = 0; l < NL; ++l) {
        k_pre<<<NN/64, 256, 0, stream>>>(hb, wcatp + (size_t)l*32768,
                                         fp[8] + (size_t)l*HID, H1, agg, upd);
        k_edge7<<<PBLK, 256, 0, stream>>>(H1, rS, cS, pos,
            fp[7] + (size_t)l*257*HID + 256*HID,       // w1c (d2 row, f32)
            w2p + (size_t)l*16384, fp[10] + (size_t)l*HID,
            c1p + (size_t)l*16384, fp[16] + (size_t)l*HID,
            fp[17] + (size_t)l*HID,
            agg, upd);
        k_node_mfma<<<NN/64, 256, 0, stream>>>(hb, agg,
            nw1p + (size_t)l*32768, fp[12] + (size_t)l*HID,
            nw2p + (size_t)l*16384, fp[14] + (size_t)l*HID,
            fp[18] + (size_t)l*HID, fp[19] + (size_t)l*HID,
            pos, upd, rowStart);
    }
    k_head<<<NN/4, 256, 0, stream>>>(hb, pos, fp[20], fp[21], fp[22], fp[23],
                                     d_out, flags);
}

// Round 12
// 647.436 us; speedup vs baseline: 1.4613x; 1.0490x over previous
//
#include <hip/hip_runtime.h>
#include <hip/hip_bf16.h>

#define BB 512
#define NA 58
#define LAT 64
#define HID 128
#define AF 10
#define NL 2
#define NN (BB*NA)      // 29696
#define NE (NN*16)      // 475136
#define ET 64           // edges per tile
#define NTILE (NE/ET)   // 7424
#define PBLK 768        // persistent blocks (3 per CU)

typedef __attribute__((ext_vector_type(8))) short s8;
typedef __attribute__((ext_vector_type(4))) float f4;

struct CvtDesc {
    const void* src[24];
    float*      dst[24];
    int         len[24];
};

struct PackJobs {
    const float* src[10];
    short*       dst[10];
    int          K[10];
    int          mode[10];
};

__device__ __forceinline__ float siluf(float x) {
    return x * __builtin_amdgcn_rcpf(1.0f + __expf(-x));
}

__device__ __forceinline__ short f2b(float x) {
    __hip_bfloat16 b = __float2bfloat16(x);
    return *(short*)&b;
}

__device__ __forceinline__ float b2f(short s) {
    return __uint_as_float(((unsigned int)(unsigned short)s) << 16);
}

// ---------------------------------------------------------------------------
__global__ void k_detect(const unsigned short* __restrict__ z16,
                         const unsigned int* __restrict__ e32,
                         int* __restrict__ flags) {
    __shared__ int sbf, si64;
    if (threadIdx.x == 0) { sbf = 0; si64 = 0; }
    __syncthreads();
    int c1 = 0, c2 = 0;
    for (int i = threadIdx.x; i < 1024; i += 256) {
        unsigned short v = z16[2*i];
        int e = (v >> 7) & 0xFF;
        if (e >= 100 && e <= 140) c1++;
        if (e32[2*i + 1] == 0u) c2++;
    }
    atomicAdd(&sbf, c1);
    atomicAdd(&si64, c2);
    __syncthreads();
    if (threadIdx.x == 0) {
        flags[0] = (sbf  > 600) ? 1 : 0;
        flags[1] = (si64 > 600) ? 1 : 0;
    }
}

__global__ void k_convert(CvtDesc d, const int* __restrict__ flags) {
    int a = blockIdx.y;
    int i = blockIdx.x * blockDim.x + threadIdx.x;
    int n = d.len[a];
    if (i >= n) return;
    if (flags[0]) {
        d.dst[a][i] = __bfloat162float(((const __hip_bfloat16*)d.src[a])[i]);
    } else {
        d.dst[a][i] = ((const float*)d.src[a])[i];
    }
}

__global__ void k_packall(PackJobs pj) {
    int j = blockIdx.y;
    int idx = blockIdx.x * 256 + threadIdx.x;
    const float* w = pj.src[j];
    short* o = pj.dst[j];
    if (pj.mode[j] == 0) {
        int K = pj.K[j];
        if (idx >= 128*K) return;
        int jj = idx & 7;
        int l  = (idx >> 3) & 63;
        int rest = idx >> 9;
        int KC = K >> 5;
        int kc = rest % KC;
        int nt = rest / KC;
        int n = nt*16 + (l & 15);
        int k = kc*32 + (l >> 4)*8 + jj;
        o[idx] = f2b(w[k*128 + n]);
    } else {
        if (idx >= 32768) return;
        int jj = idx & 7;
        int l  = (idx >> 3) & 63;
        int rest = idx >> 9;
        int kc = rest & 3;
        int nt = rest >> 2;
        int n = nt*16 + (l & 15);
        int k = kc*32 + (l >> 4)*8 + jj;
        float v = (n < 128) ? w[k*128 + n] : w[(128 + k)*128 + (n - 128)];
        o[idx] = f2b(v);
    }
}

// ---------------------------------------------------------------------------
__global__ void k_hist(const int* __restrict__ eidx, const int* __restrict__ flags,
                       int* __restrict__ cnt) {
    int e = blockIdx.x * 256 + threadIdx.x;
    if (e >= NE) return;
    int is64 = flags[1];
    int r = eidx[is64 ? 2*(long)e : (long)e];
    atomicAdd(&cnt[r], 1);
}

__global__ __launch_bounds__(1024) void k_scan(const int* __restrict__ cnt,
                                               int* __restrict__ rowStart,
                                               int* __restrict__ cursor) {
    __shared__ int part[1024];
    int t = threadIdx.x;
    int base = t * 29;                    // NN == 1024*29
    int loc[29];
    int s = 0;
    #pragma unroll
    for (int i = 0; i < 29; ++i) { loc[i] = s; s += cnt[base + i]; }
    part[t] = s;
    __syncthreads();
    for (int d = 1; d < 1024; d <<= 1) {
        int v = (t >= d) ? part[t - d] : 0;
        __syncthreads();
        part[t] += v;
        __syncthreads();
    }
    int pre = (t == 0) ? 0 : part[t - 1];
    #pragma unroll
    for (int i = 0; i < 29; ++i) {
        int v = pre + loc[i];
        rowStart[base + i] = v;
        cursor[base + i] = v;
    }
    if (t == 1023) rowStart[NN] = pre + s;
}

__global__ void k_scatter(const int* __restrict__ eidx, const int* __restrict__ flags,
                          int* __restrict__ cursor,
                          int* __restrict__ rS, int* __restrict__ cS) {
    int e = blockIdx.x * 256 + threadIdx.x;
    if (e >= NE) return;
    int is64 = flags[1];
    long ge = e, gc = (long)e + NE;
    int r = eidx[is64 ? 2*ge : ge];
    int c = eidx[is64 ? 2*gc : gc];
    int p = atomicAdd(&cursor[r], 1);
    rS[p] = r; cS[p] = c;
}

// ---------------------------------------------------------------------------
__global__ void k_hz(const float* __restrict__ z, const float* __restrict__ lw,
                     const float* __restrict__ lb, float* __restrict__ hz) {
    __shared__ float zs[LAT];
    int b = blockIdx.x;
    int c = threadIdx.x;
    if (c < LAT) zs[c] = z[b*LAT + c];
    __syncthreads();
    float acc = lb[c];
    #pragma unroll
    for (int k = 0; k < LAT; ++k) acc += zs[k] * lw[k*HID + c];
    hz[b*HID + c] = acc;
}

// ---------------------------------------------------------------------------
// init3: h init (bf16) + pos init + zero agg/upd + H1(layer0) GEMM. 64 nodes/blk.
__global__ __launch_bounds__(256) void k_init3(
    const float* __restrict__ hz, const float* __restrict__ at,
    const float* __restrict__ aw, const float* __restrict__ ab,
    const float* __restrict__ ic,
    float* __restrict__ pos, short* __restrict__ hb,
    const short* __restrict__ wcat0, const float* __restrict__ b10,
    short* __restrict__ H1, float* __restrict__ agg, float* __restrict__ upd)
{
    __shared__ short x[64][136];
    __shared__ float awS[AF][HID];
    __shared__ float atS[64][AF+2];
    const int tid = threadIdx.x;
    const int n0 = blockIdx.x * 64;

    for (int i = tid; i < AF*HID; i += 256) awS[i/HID][i%HID] = aw[i];
    for (int i = tid; i < 64*AF; i += 256)
        atS[i/AF][i%AF] = at[(long)(n0 + i/AF)*AF + i%AF];
    __syncthreads();

    #pragma unroll
    for (int it = 0; it < 32; ++it) {
        int idx = it*256 + tid;
        int r = idx >> 7, c = idx & 127;
        int n = n0 + r;
        int bb = n / NA;
        float v = hz[bb*HID + c] + ab[c];
        #pragma unroll
        for (int f = 0; f < AF; ++f) v += atS[r][f]*awS[f][c];
        short s = f2b(v);
        x[r][c] = s;
        hb[(long)n*HID + c] = s;
    }
    if (tid < 192) {
        int i = tid/3, d = tid - i*3;
        int n = n0 + i;
        pos[n*3 + d] = ic[(n % NA)*3 + d];
        upd[n*3 + d] = 0.f;
    }
    {
        f4* a4 = (f4*)(agg + (long)n0*HID);
        for (int j = tid; j < 64*HID/4; j += 256) a4[j] = (f4)0.f;
    }
    __syncthreads();

    const int l = tid & 63, w = tid >> 6;
    const int l16 = l & 15, quad = l >> 4;
    f4 acc[4][4];
    #pragma unroll
    for (int mt = 0; mt < 4; ++mt)
        #pragma unroll
        for (int nt4 = 0; nt4 < 4; ++nt4) acc[mt][nt4] = (f4)0.f;
    #pragma unroll
    for (int kc = 0; kc < 4; ++kc) {
        s8 a[4];
        #pragma unroll
        for (int mt = 0; mt < 4; ++mt)
            a[mt] = *(const s8*)&x[mt*16 + l16][kc*32 + quad*8];
        #pragma unroll
        for (int nt4 = 0; nt4 < 4; ++nt4) {
            int nt = w*4 + nt4;
            s8 b = *(const s8*)(wcat0 + (((size_t)nt*4 + kc)*64 + l)*8);
            #pragma unroll
            for (int mt = 0; mt < 4; ++mt)
                acc[mt][nt4] = __builtin_amdgcn_mfma_f32_16x16x32_bf16(a[mt], b, acc[mt][nt4], 0, 0, 0);
        }
    }
    #pragma unroll
    for (int nt4 = 0; nt4 < 4; ++nt4) {
        int col = (w*4 + nt4)*16 + l16;
        float bias = (col < 128) ? b10[col] : 0.f;
        #pragma unroll
        for (int mt = 0; mt < 4; ++mt)
            #pragma unroll
            for (int i = 0; i < 4; ++i) {
                int row = mt*16 + quad*4 + i;
                H1[(long)(n0 + row)*256 + col] = f2b(acc[mt][nt4][i] + bias);
            }
    }
}

// ---------------------------------------------------------------------------
// Edge kernel v8: double-buffered t1, 2 barriers/tile, gathers for tile T+1
// interleaved 1:1 with stage2 MFMA of tile T (no state across barriers).
__global__ __launch_bounds__(256, 3) void k_edge8(
    const short* __restrict__ H1,
    const int* __restrict__ rS, const int* __restrict__ cS,
    const float* __restrict__ pos,
    const float* __restrict__ w1c,
    const short* __restrict__ w2p, const float* __restrict__ b2,
    const short* __restrict__ c1p, const float* __restrict__ cb1,
    const float* __restrict__ cw2,
    float* __restrict__ agg, float* __restrict__ upd)
{
    __shared__ short t1[2][ET][136];
    __shared__ short mm[ET][136];
    __shared__ int   rIs[2][ET], cIs[2][ET];
    __shared__ float sred[ET];

    const int tid = threadIdx.x;
    const int l = tid & 63, w = tid >> 6;
    const int l16 = l & 15, quad = l >> 4;
    const int c0 = (2*w)*16 + l16, c1c = (2*w+1)*16 + l16;
    const int half = tid >> 7, ch = tid & 127;
    const int q = tid & 15;
    const int esub = tid >> 4;

    float wv[8];
    #pragma unroll
    for (int j = 0; j < 8; ++j) wv[j] = w1c[q*8 + j];

    s8 w2f[8], c1f[8];
    #pragma unroll
    for (int kc = 0; kc < 4; ++kc) {
        w2f[kc]     = *(const s8*)(w2p + (((size_t)(2*w)*4 + kc)*64 + l)*8);
        w2f[4 + kc] = *(const s8*)(w2p + (((size_t)(2*w+1)*4 + kc)*64 + l)*8);
        c1f[kc]     = *(const s8*)(c1p + (((size_t)(2*w)*4 + kc)*64 + l)*8);
        c1f[4 + kc] = *(const s8*)(c1p + (((size_t)(2*w+1)*4 + kc)*64 + l)*8);
    }
    const float bia2_0 = b2[c0],  bia2_1 = b2[c1c];
    const float biac_0 = cb1[c0], biac_1 = cb1[c1c];
    const float cw0    = cw2[c0], cw1v   = cw2[c1c];

    int   pri[4], pci[4];
    float pd2[4];
    auto PREIDX = [&](int T) {
        long eb = (long)T * ET;
        #pragma unroll
        for (int it = 0; it < 4; ++it) {
            int e = esub + 16*it;
            int r = rS[eb + e], c = cS[eb + e];
            pri[it] = r; pci[it] = c;
            float rx = pos[r*3+0] - pos[c*3+0];
            float ry = pos[r*3+1] - pos[c*3+1];
            float rz = pos[r*3+2] - pos[c*3+2];
            pd2[it] = fminf(fmaxf(rx*rx + ry*ry + rz*rz, 1e-6f), 1e6f);
        }
    };

    // ---- prologue: build tile T into t1[0]
    int T = blockIdx.x;
    PREIDX(T);
    #pragma unroll
    for (int it = 0; it < 4; ++it) {
        s8 va = *(const s8*)(H1 + (long)pri[it]*256 + q*8);
        s8 vb = *(const s8*)(H1 + (long)pci[it]*256 + 128 + q*8);
        float d2 = pd2[it];
        s8 o;
        #pragma unroll
        for (int j = 0; j < 8; ++j)
            o[j] = f2b(siluf(b2f(va[j]) + b2f(vb[j]) + d2*wv[j]));
        *(s8*)&t1[0][esub + 16*it][q*8] = o;
    }
    if (q == 0) {
        #pragma unroll
        for (int it = 0; it < 4; ++it) {
            rIs[0][esub + 16*it] = pri[it];
            cIs[0][esub + 16*it] = pci[it];
        }
    }
    if (tid < ET) sred[tid] = 0.f;
    int Tn = T + PBLK;
    if (Tn < NTILE) PREIDX(Tn);
    __syncthreads();

    int b = 0;
    while (true) {
        const bool hasNext = (Tn < NTILE);

        // ---- half1: stage2(T) from t1[b]  ⊗  build t1[b^1](Tn)
        {
            f4 acc[4][2];
            #pragma unroll
            for (int mt = 0; mt < 4; ++mt) { acc[mt][0] = (f4)0.f; acc[mt][1] = (f4)0.f; }
            #pragma unroll
            for (int it = 0; it < 4; ++it) {
                s8 va, vb;
                if (hasNext) {
                    va = *(const s8*)(H1 + (long)pri[it]*256 + q*8);
                    vb = *(const s8*)(H1 + (long)pci[it]*256 + 128 + q*8);
                }
                #pragma unroll
                for (int mt = 0; mt < 4; ++mt) {
                    s8 a = *(const s8*)&t1[b][mt*16 + l16][it*32 + quad*8];
                    acc[mt][0] = __builtin_amdgcn_mfma_f32_16x16x32_bf16(a, w2f[it],     acc[mt][0], 0, 0, 0);
                    acc[mt][1] = __builtin_amdgcn_mfma_f32_16x16x32_bf16(a, w2f[4 + it], acc[mt][1], 0, 0, 0);
                }
                if (hasNext) {
                    float d2 = pd2[it];
                    s8 o;
                    #pragma unroll
                    for (int j = 0; j < 8; ++j)
                        o[j] = f2b(siluf(b2f(va[j]) + b2f(vb[j]) + d2*wv[j]));
                    *(s8*)&t1[b^1][esub + 16*it][q*8] = o;
                }
            }
            if (hasNext && q == 0) {
                #pragma unroll
                for (int it = 0; it < 4; ++it) {
                    rIs[b^1][esub + 16*it] = pri[it];
                    cIs[b^1][esub + 16*it] = pci[it];
                }
            }
            #pragma unroll
            for (int mt = 0; mt < 4; ++mt) {
                #pragma unroll
                for (int i = 0; i < 4; ++i) {
                    int row = mt*16 + quad*4 + i;
                    mm[row][c0]  = f2b(siluf(acc[mt][0][i] + bia2_0));
                    mm[row][c1c] = f2b(siluf(acc[mt][1][i] + bia2_1));
                }
            }
        }
        __syncthreads();                 // (1) mm + t1[b^1] + meta ready

        // ---- half2: stage3(T) + agg(T) + PREIDX(T+2)
        {
            f4 acc[4][2];
            #pragma unroll
            for (int mt = 0; mt < 4; ++mt) { acc[mt][0] = (f4)0.f; acc[mt][1] = (f4)0.f; }
            #pragma unroll
            for (int kc = 0; kc < 4; ++kc) {
                #pragma unroll
                for (int mt = 0; mt < 4; ++mt) {
                    s8 a = *(const s8*)&mm[mt*16 + l16][kc*32 + quad*8];
                    acc[mt][0] = __builtin_amdgcn_mfma_f32_16x16x32_bf16(a, c1f[kc],     acc[mt][0], 0, 0, 0);
                    acc[mt][1] = __builtin_amdgcn_mfma_f32_16x16x32_bf16(a, c1f[4 + kc], acc[mt][1], 0, 0, 0);
                }
            }
            #pragma unroll
            for (int mt = 0; mt < 4; ++mt) {
                #pragma unroll
                for (int i = 0; i < 4; ++i) {
                    float p = siluf(acc[mt][0][i] + biac_0) * cw0
                            + siluf(acc[mt][1][i] + biac_1) * cw1v;
                    p += __shfl_xor(p, 1);
                    p += __shfl_xor(p, 2);
                    p += __shfl_xor(p, 4);
                    p += __shfl_xor(p, 8);
                    if (l16 == 0) {
                        int row = mt*16 + quad*4 + i;
                        atomicAdd(&sred[row], p);
                    }
                }
            }
        }
        {
            int e0 = half * 32;
            int cur = rIs[b][e0];
            float a = 0.f;
            #pragma unroll
            for (int e = e0; e < e0 + 32; ++e) {
                int r = rIs[b][e];
                if (r != cur) {
                    atomicAdd(&agg[(long)cur*HID + ch], a);
                    a = 0.f; cur = r;
                }
                a += b2f(mm[e][ch]);
            }
            atomicAdd(&agg[(long)cur*HID + ch], a);
        }
        int Tnn = Tn + PBLK;
        if (hasNext && Tnn < NTILE) PREIDX(Tnn);
        __syncthreads();                 // (2) sred complete, mm consumed

        // ---- upd(T): races with nothing until barrier (1) of next iter
        if (tid < ET) {
            float cwv = fminf(fmaxf(sred[tid], -1.f), 1.f);
            sred[tid] = 0.f;
            int r = rIs[b][tid], c = cIs[b][tid];
            float rx = pos[r*3+0] - pos[c*3+0];
            float ry = pos[r*3+1] - pos[c*3+1];
            float rz = pos[r*3+2] - pos[c*3+2];
            atomicAdd(&upd[r*3+0], cwv*rx);
            atomicAdd(&upd[r*3+1], cwv*ry);
            atomicAdd(&upd[r*3+2], cwv*rz);
        }
        if (!hasNext) break;
        T = Tn; Tn = Tnn; b ^= 1;
    }
}

// ---------------------------------------------------------------------------
// Node kernel + fused H1(next layer) + agg/upd zeroing for next layer.
__global__ __launch_bounds__(256) void k_node_mfma(
    short* __restrict__ hb, float* __restrict__ agg,
    const short* __restrict__ w1p, const float* __restrict__ b1n,
    const short* __restrict__ w2p, const float* __restrict__ b2n,
    const float* __restrict__ lg, const float* __restrict__ lb,
    float* __restrict__ pos, float* __restrict__ upd,
    const int* __restrict__ rowStart,
    const short* __restrict__ wcatn, const float* __restrict__ b1next,
    short* __restrict__ H1)
{
    __shared__ short x[64][264];
    __shared__ short t1[64][144];
    __shared__ float mus[64], rstds[64];
    float (*hn)[132] = (float (*)[132])&x[0][0];

    const int tid = threadIdx.x;
    const int n0 = blockIdx.x * 64;

    #pragma unroll
    for (int it = 0; it < 4; ++it) {
        int idx = it*256 + tid;
        int e = idx >> 4, qq = idx & 15;
        *(int4*)&x[e][qq*8] = *(const int4*)(hb + (long)(n0+e)*HID + qq*8);
    }
    #pragma unroll
    for (int it = 0; it < 8; ++it) {
        int idx = it*256 + tid;
        int e = idx >> 5, qq = idx & 31;
        float4 v = *(const float4*)(agg + (long)(n0+e)*HID + qq*4);
        short4 sv;
        sv.x = f2b(v.x); sv.y = f2b(v.y); sv.z = f2b(v.z); sv.w = f2b(v.w);
        *(short4*)&x[e][128 + qq*4] = sv;
    }
    __syncthreads();

    // zero agg rows for next layer (fully staged above)
    {
        f4* a4 = (f4*)(agg + (long)n0*HID);
        for (int j = tid; j < 64*HID/4; j += 256) a4[j] = (f4)0.f;
    }

    const int l = tid & 63, w = tid >> 6;
    const int l16 = l & 15, quad = l >> 4;
    const int nt0 = 2*w, nt1 = 2*w + 1;
    const int c0 = nt0*16 + l16, c1c = nt1*16 + l16;

    {
        f4 acc[4][2];
        #pragma unroll
        for (int mt = 0; mt < 4; ++mt) { acc[mt][0] = (f4)0.f; acc[mt][1] = (f4)0.f; }
        #pragma unroll
        for (int kc = 0; kc < 8; ++kc) {
            s8 b0  = *(const s8*)(w1p + (((size_t)nt0*8 + kc)*64 + l)*8);
            s8 b1f = *(const s8*)(w1p + (((size_t)nt1*8 + kc)*64 + l)*8);
            #pragma unroll
            for (int mt = 0; mt < 4; ++mt) {
                s8 a = *(const s8*)&x[mt*16 + l16][kc*32 + quad*8];
                acc[mt][0] = __builtin_amdgcn_mfma_f32_16x16x32_bf16(a, b0,  acc[mt][0], 0, 0, 0);
                acc[mt][1] = __builtin_amdgcn_mfma_f32_16x16x32_bf16(a, b1f, acc[mt][1], 0, 0, 0);
            }
        }
        float bia0 = b1n[c0], bia1 = b1n[c1c];
        #pragma unroll
        for (int mt = 0; mt < 4; ++mt) {
            #pragma unroll
            for (int i = 0; i < 4; ++i) {
                int row = mt*16 + quad*4 + i;
                t1[row][c0]  = f2b(siluf(acc[mt][0][i] + bia0));
                t1[row][c1c] = f2b(siluf(acc[mt][1][i] + bia1));
            }
        }
    }
    __syncthreads();

    {
        f4 acc[4][2];
        #pragma unroll
        for (int mt = 0; mt < 4; ++mt) { acc[mt][0] = (f4)0.f; acc[mt][1] = (f4)0.f; }
        #pragma unroll
        for (int kc = 0; kc < 4; ++kc) {
            s8 b0  = *(const s8*)(w2p + (((size_t)nt0*4 + kc)*64 + l)*8);
            s8 b1f = *(const s8*)(w2p + (((size_t)nt1*4 + kc)*64 + l)*8);
            #pragma unroll
            for (int mt = 0; mt < 4; ++mt) {
                s8 a = *(const s8*)&t1[mt*16 + l16][kc*32 + quad*8];
                acc[mt][0] = __builtin_amdgcn_mfma_f32_16x16x32_bf16(a, b0,  acc[mt][0], 0, 0, 0);
                acc[mt][1] = __builtin_amdgcn_mfma_f32_16x16x32_bf16(a, b1f, acc[mt][1], 0, 0, 0);
            }
        }
        float bia0 = b2n[c0], bia1 = b2n[c1c];
        __syncthreads();
        #pragma unroll
        for (int mt = 0; mt < 4; ++mt) {
            #pragma unroll
            for (int i = 0; i < 4; ++i) {
                int row = mt*16 + quad*4 + i;
                hn[row][c0]  = acc[mt][0][i] + bia0;
                hn[row][c1c] = acc[mt][1][i] + bia1;
            }
        }
    }
    __syncthreads();

    {
        int r = tid >> 2, part = tid & 3;
        float s = 0.f, qv = 0.f;
        #pragma unroll
        for (int j = 0; j < 32; ++j) {
            float v = hn[r][part + 4*j];
            s += v; qv += v*v;
        }
        s += __shfl_xor(s, 1); qv += __shfl_xor(qv, 1);
        s += __shfl_xor(s, 2); qv += __shfl_xor(qv, 2);
        if (part == 0) {
            float mu = s * (1.0f/HID);
            float var = qv * (1.0f/HID) - mu*mu;
            mus[r] = mu;
            rstds[r] = rsqrtf(var + 1e-5f);
        }
    }
    __syncthreads();

    #pragma unroll
    for (int it = 0; it < 32; ++it) {
        int idx = it*256 + tid;
        int r = idx >> 7, c = idx & 127;
        float v = (hn[r][c] - mus[r]) * rstds[r] * lg[c] + lb[c];
        short s = f2b(v);
        hb[(long)(n0 + r)*HID + c] = s;
        t1[r][c] = s;                       // stage for H1(next)
    }
    if (tid < 192) {
        int i = tid / 3, d = tid - i*3;
        int n = n0 + i;
        float dg = (float)(rowStart[n+1] - rowStart[n]);
        pos[n*3+d] += upd[n*3+d] / (dg + 1e-6f);
        upd[n*3+d] = 0.f;                   // zero for next layer
    }

    if (wcatn) {
        __syncthreads();
        f4 acc[4][4];
        #pragma unroll
        for (int mt = 0; mt < 4; ++mt)
            #pragma unroll
            for (int nt4 = 0; nt4 < 4; ++nt4) acc[mt][nt4] = (f4)0.f;
        #pragma unroll
        for (int kc = 0; kc < 4; ++kc) {
            s8 a[4];
            #pragma unroll
            for (int mt = 0; mt < 4; ++mt)
                a[mt] = *(const s8*)&t1[mt*16 + l16][kc*32 + quad*8];
            #pragma unroll
            for (int nt4 = 0; nt4 < 4; ++nt4) {
                int nt = w*4 + nt4;
                s8 b = *(const s8*)(wcatn + (((size_t)nt*4 + kc)*64 + l)*8);
                #pragma unroll
                for (int mt = 0; mt < 4; ++mt)
                    acc[mt][nt4] = __builtin_amdgcn_mfma_f32_16x16x32_bf16(a[mt], b, acc[mt][nt4], 0, 0, 0);
            }
        }
        #pragma unroll
        for (int nt4 = 0; nt4 < 4; ++nt4) {
            int col = (w*4 + nt4)*16 + l16;
            float bias = (col < 128) ? b1next[col] : 0.f;
            #pragma unroll
            for (int mt = 0; mt < 4; ++mt)
                #pragma unroll
                for (int i = 0; i < 4; ++i) {
                    int row = mt*16 + quad*4 + i;
                    H1[(long)(n0 + row)*256 + col] = f2b(acc[mt][nt4][i] + bias);
                }
        }
    }
}

// ---------------------------------------------------------------------------
__global__ void k_head(const short* __restrict__ hb, const float* __restrict__ pos,
                       const float* __restrict__ w1, const float* __restrict__ b1,
                       const float* __restrict__ w2, const float* __restrict__ b2,
                       void* __restrict__ out, const int* __restrict__ flags)
{
    __shared__ float hs[4][HID];
    __shared__ float t[4][64];
    const int tid = threadIdx.x;
    const int n0 = blockIdx.x * 4;
    for (int i = tid; i < 4*HID; i += 256)
        hs[i >> 7][i & 127] = b2f(hb[(long)n0*HID + i]);
    __syncthreads();
    const int s = tid >> 6, c = tid & 63;
    float acc = b1[c];
    for (int k4 = 0; k4 < 32; ++k4) {
        int k = k4*4;
        float wa = w1[(k+0)*64 + c];
        float wb = w1[(k+1)*64 + c];
        float wc = w1[(k+2)*64 + c];
        float wd = w1[(k+3)*64 + c];
        float4 v = *(const float4*)&hs[s][k];
        acc += v.x*wa + v.y*wb + v.z*wc + v.w*wd;
    }
    t[s][c] = siluf(acc);
    __syncthreads();
    if (c < 3) {
        float a2 = b2[c];
        #pragma unroll
        for (int k = 0; k < 64; ++k) a2 += t[s][k] * w2[k*3 + c];
        int n = n0 + s;
        float v = pos[n*3+c] + a2;
        if (flags[0]) ((__hip_bfloat16*)out)[n*3+c] = __float2bfloat16(v);
        else          ((float*)out)[n*3+c] = v;
    }
}

// ---------------------------------------------------------------------------
extern "C" void kernel_launch(void* const* d_in, const int* in_sizes, int n_in,
                              void* d_out, int out_size, void* d_ws, size_t ws_size,
                              hipStream_t stream)
{
    (void)in_sizes; (void)n_in; (void)out_size; (void)ws_size;

    int* flags = (int*)d_ws;
    float* base = (float*)d_ws;
    size_t off = 64;
    auto alloc = [&](size_t n) { float* p = base + off; off += (n + 63) & ~63ull; return p; };

    static const int aidx[24] = {0,1,3,4,5,6,7,8,9,10,11,12,13,14,15,16,17,18,19,20,21,22,23,24};
    static const int alen[24] = {
        BB*LAT, NN*AF, NA*3, LAT*HID, HID, AF*HID, HID,
        NL*257*HID, NL*HID, NL*HID*HID, NL*HID,
        NL*256*HID, NL*HID, NL*HID*HID, NL*HID,
        NL*HID*HID, NL*HID, NL*HID, NL*HID, NL*HID,
        HID*64, 64, 64*3, 3
    };
    CvtDesc cd;
    float* fp[24];
    for (int a = 0; a < 24; ++a) {
        fp[a] = alloc((size_t)alen[a]);
        cd.src[a] = d_in[aidx[a]];
        cd.dst[a] = fp[a];
        cd.len[a] = alen[a];
    }
    float* agg = alloc((size_t)NN*HID);
    float* hz  = alloc((size_t)BB*HID);
    float* pos = alloc((size_t)NN*3);
    float* upd = alloc((size_t)NN*3);
    short* hb  = (short*)alloc((size_t)NN*HID/2);
    short* H1  = (short*)alloc((size_t)NN*256/2);
    short* wcatp = (short*)alloc((size_t)NL*32768/2);
    short* w2p = (short*)alloc((size_t)NL*16384/2);
    short* c1p = (short*)alloc((size_t)NL*16384/2);
    short* nw1p = (short*)alloc((size_t)NL*32768/2);
    short* nw2p = (short*)alloc((size_t)NL*16384/2);
    int* cnt      = (int*)alloc((size_t)NN);
    int* rowStart = (int*)alloc((size_t)NN + 1);
    int* cursor   = (int*)alloc((size_t)NN);
    int* rS       = (int*)alloc((size_t)NE);
    int* cS       = (int*)alloc((size_t)NE);
    const int* eidx = (const int*)d_in[2];

    k_detect<<<1, 256, 0, stream>>>((const unsigned short*)d_in[0],
                                    (const unsigned int*)d_in[2], flags);
    k_convert<<<dim3((NN*AF + 255)/256, 24), 256, 0, stream>>>(cd, flags);

    PackJobs pj;
    for (int l = 0; l < NL; ++l) {
        int b5 = l*5;
        pj.src[b5+0] = fp[7]  + (size_t)l*257*HID; pj.dst[b5+0] = wcatp + (size_t)l*32768; pj.K[b5+0] = 256; pj.mode[b5+0] = 1;
        pj.src[b5+1] = fp[9]  + (size_t)l*HID*HID; pj.dst[b5+1] = w2p   + (size_t)l*16384; pj.K[b5+1] = 128; pj.mode[b5+1] = 0;
        pj.src[b5+2] = fp[15] + (size_t)l*HID*HID; pj.dst[b5+2] = c1p   + (size_t)l*16384; pj.K[b5+2] = 128; pj.mode[b5+2] = 0;
        pj.src[b5+3] = fp[11] + (size_t)l*256*HID; pj.dst[b5+3] = nw1p  + (size_t)l*32768; pj.K[b5+3] = 256; pj.mode[b5+3] = 0;
        pj.src[b5+4] = fp[13] + (size_t)l*HID*HID; pj.dst[b5+4] = nw2p  + (size_t)l*16384; pj.K[b5+4] = 128; pj.mode[b5+4] = 0;
    }
    k_packall<<<dim3(128, 10), 256, 0, stream>>>(pj);

    // counting sort edges by row
    hipMemsetAsync(cnt, 0, (size_t)NN*sizeof(int), stream);
    k_hist<<<(NE + 255)/256, 256, 0, stream>>>(eidx, flags, cnt);
    k_scan<<<1, 1024, 0, stream>>>(cnt, rowStart, cursor);
    k_scatter<<<(NE + 255)/256, 256, 0, stream>>>(eidx, flags, cursor, rS, cS);

    k_hz<<<BB, HID, 0, stream>>>(fp[0], fp[3], fp[4], hz);
    k_init3<<<NN/64, 256, 0, stream>>>(hz, fp[1], fp[5], fp[6], fp[2], pos, hb,
                                       wcatp, fp[8], H1, agg, upd);

    for (int l = 0; l < NL; ++l) {
        k_edge8<<<PBLK, 256, 0, stream>>>(H1, rS, cS, pos,
            fp[7] + (size_t)l*257*HID + 256*HID,       // w1c (d2 row, f32)
            w2p + (size_t)l*16384, fp[10] + (size_t)l*HID,
            c1p + (size_t)l*16384, fp[16] + (size_t)l*HID,
            fp[17] + (size_t)l*HID,
            agg, upd);
        const short* wcatn = (l+1 < NL) ? (wcatp + (size_t)(l+1)*32768) : nullptr;
        const float* b1nx  = (l+1 < NL) ? (fp[8] + (size_t)(l+1)*HID) : fp[8];
        k_node_mfma<<<NN/64, 256, 0, stream>>>(hb, agg,
            nw1p + (size_t)l*32768, fp[12] + (size_t)l*HID,
            nw2p + (size_t)l*16384, fp[14] + (size_t)l*HID,
            fp[18] + (size_t)l*HID, fp[19] + (size_t)l*HID,
            pos, upd, rowStart, wcatn, b1nx, H1);
    }
    k_head<<<NN/4, 256, 0, stream>>>(hb, pos, fp[20], fp[21], fp[22], fp[23],
                                     d_out, flags);
}